// Round 6
// baseline (3511.031 us; speedup 1.0000x reference)
//
#include <hip/hip_runtime.h>
#include <math.h>

// NormalConsistencyLoss: B=4, N=8192, D=3, K=16, fp32 in/out (scalar out).
// Pipeline:
//  [build_kernel]  per cloud: Morton-sort points (bitonic in LDS), store
//                  sorted float4(x,y,z,sq) + orig idx + per-16-chunk AABBs.
//  [knn_kernel]    1 lane = 1 query (Morton order): seed top-16 from home
//                  chunks, wave-level AABB prune (conservative margin),
//                  exact lex (d2,idx) selection, PCA normal via faithful
//                  LAPACK ssyevd(fp32) port -> normals[orig idx].
//  [loss_partial/loss_final] 1 - mean(dot).
// Selection is set-unique under lex order => bit-identical to lax.top_k.

#define NPTS   8192
#define NB     4
#define NCHUNK 512
#define MARGIN 1e-4f

// ---------------- LAPACK single-precision ports (sign-faithful) ----------------

__device__ __forceinline__ float slapy2f(float x, float y){
#pragma clang fp contract(off)
  float xa = fabsf(x), ya = fabsf(y);
  float w = fmaxf(xa, ya), z = fminf(xa, ya);
  if (z == 0.f) return w;
  float t = z / w;
  return w * sqrtf(1.f + t*t);
}

// LAPACK >= 3.10 slartg
__device__ __forceinline__ void slartgf(float f, float g, float& c, float& s, float& r){
#pragma clang fp contract(off)
  const float safmin = 1.17549435e-38f;
  const float safmax = 8.50705917e37f;
  const float rtmin  = 1.08420217e-19f;
  const float rtmax  = 6.52318604e18f;
  if (g == 0.f){ c = 1.f; s = 0.f; r = f; }
  else if (f == 0.f){ c = 0.f; s = copysignf(1.f, g); r = fabsf(g); }
  else {
    float f1 = fabsf(f), g1 = fabsf(g);
    if (f1 > rtmin && f1 < rtmax && g1 > rtmin && g1 < rtmax){
      float d = sqrtf(f*f + g*g);
      c = f1 / d;
      r = copysignf(d, f);
      s = g / r;
    } else {
      float u = fminf(safmax, fmaxf(safmin, fmaxf(f1, g1)));
      float fs = f/u, gs = g/u;
      float d = sqrtf(fs*fs + gs*gs);
      c = fabsf(fs)/d;
      r = copysignf(d, f);
      r = r*u;
      s = g/r;
    }
  }
}

__device__ __forceinline__ void slaev2f(float a, float b, float cc,
                                        float& rt1, float& rt2, float& cs1, float& sn1){
#pragma clang fp contract(off)
  float sm  = a + cc;
  float df  = a - cc;
  float adf = fabsf(df);
  float tb  = b + b;
  float ab  = fabsf(tb);
  float acmx, acmn;
  if (fabsf(a) > fabsf(cc)){ acmx = a; acmn = cc; } else { acmx = cc; acmn = a; }
  float rt;
  if (adf > ab){ float t = ab/adf; rt = adf*sqrtf(1.f + t*t); }
  else if (adf < ab){ float t = adf/ab; rt = ab*sqrtf(1.f + t*t); }
  else rt = ab*sqrtf(2.f);
  int sgn1;
  if (sm < 0.f){ rt1 = 0.5f*(sm - rt); sgn1 = -1; rt2 = (acmx/rt1)*acmn - (b/rt1)*b; }
  else if (sm > 0.f){ rt1 = 0.5f*(sm + rt); sgn1 = 1; rt2 = (acmx/rt1)*acmn - (b/rt1)*b; }
  else { rt1 = 0.5f*rt; rt2 = -0.5f*rt; sgn1 = 1; }
  int sgn2; float cs;
  if (df >= 0.f){ cs = df + rt; sgn2 = 1; } else { cs = df - rt; sgn2 = -1; }
  float acs = fabsf(cs);
  if (acs > ab){ float ct = -tb/cs; sn1 = 1.f/sqrtf(1.f + ct*ct); cs1 = ct*sn1; }
  else {
    if (ab == 0.f){ cs1 = 1.f; sn1 = 0.f; }
    else { float tn = -cs/tb; cs1 = 1.f/sqrtf(1.f + tn*tn); sn1 = tn*cs1; }
  }
  if (sgn1 == sgn2){ float tn = cs1; cs1 = -sn1; sn1 = tn; }
}

__device__ __forceinline__ void rot2(float z[3][3], int ja, float c, float s){
#pragma clang fp contract(off)
  #pragma unroll
  for (int i = 0; i < 3; ++i){
    float t1 = z[i][ja+1];
    float t0 = z[i][ja];
    z[i][ja+1] = c*t1 - s*t0;
    z[i][ja]   = s*t1 + c*t0;
  }
}

// Faithful port of LAPACK ssteqr('I', n=3, d, e, z)
__device__ __noinline__ void ssteqr3(float* d, float* e, float z[3][3]){
#pragma clang fp contract(off)
  const float eps    = 5.96046448e-08f;
  const float eps2   = 3.55271368e-15f;
  const float safmin = 1.17549435e-38f;
  const float ssfmax = 3.07445735e+18f;
  const float ssfmin = 3.05175781e-05f;
  const int n = 3;
  float cw[2], sw[2];
  int nmaxit, jtot, l1, l, lsv, lend, lendsv, m, iscale, i, j, ii, k;
  float anorm, p, g, r, c, s, f, b, rt1, rt2, tst, mul;

  for (i = 0; i < 3; ++i) for (j = 0; j < 3; ++j) z[i][j] = (i == j) ? 1.f : 0.f;
  nmaxit = n*30; jtot = 0; l1 = 1; m = 0; iscale = 0; anorm = 0.f;
  lsv = 1; lendsv = 1; lend = 1; l = 1;

L10:
  if (l1 > n) goto L160;
  if (l1 > 1) e[l1-2] = 0.f;
  if (l1 <= n-1){
    for (m = l1; m <= n-1; ++m){
      tst = fabsf(e[m-1]);
      if (tst == 0.f) goto L30;
      if (tst <= (sqrtf(fabsf(d[m-1]))*sqrtf(fabsf(d[m])))*eps){ e[m-1] = 0.f; goto L30; }
    }
  }
  m = n;
L30:
  l = l1; lsv = l; lend = m; lendsv = lend; l1 = m + 1;
  if (lend == l) goto L10;
  anorm = 0.f;
  for (i = l; i <= lend; ++i)   anorm = fmaxf(anorm, fabsf(d[i-1]));
  for (i = l; i <= lend-1; ++i) anorm = fmaxf(anorm, fabsf(e[i-1]));
  iscale = 0;
  if (anorm == 0.f) goto L10;
  if (anorm > ssfmax){
    iscale = 1; mul = ssfmax/anorm;
    for (i = l; i <= lend; ++i)   d[i-1] *= mul;
    for (i = l; i <= lend-1; ++i) e[i-1] *= mul;
  } else if (anorm < ssfmin){
    iscale = 2; mul = ssfmin/anorm;
    for (i = l; i <= lend; ++i)   d[i-1] *= mul;
    for (i = l; i <= lend-1; ++i) e[i-1] *= mul;
  }
  if (fabsf(d[lend-1]) < fabsf(d[l-1])){ lend = lsv; l = lendsv; }

  if (lend > l){
L40:
    if (l != lend){
      for (m = l; m <= lend-1; ++m){
        tst = fabsf(e[m-1]); tst = tst*tst;
        if (tst <= (eps2*fabsf(d[m-1]))*fabsf(d[m]) + safmin) goto L60;
      }
    }
    m = lend;
L60:
    if (m < lend) e[m-1] = 0.f;
    p = d[l-1];
    if (m == l) goto L80;
    if (m == l+1){
      slaev2f(d[l-1], e[l-1], d[l], rt1, rt2, c, s);
      rot2(z, l-1, c, s);
      d[l-1] = rt1; d[l] = rt2; e[l-1] = 0.f;
      l += 2;
      if (l <= lend) goto L40;
      goto L140;
    }
    if (jtot == nmaxit) goto L140;
    jtot++;
    g = (d[l] - p)/(2.f*e[l-1]);
    r = slapy2f(g, 1.f);
    g = d[m-1] - p + (e[l-1]/(g + copysignf(r, g)));
    s = 1.f; c = 1.f; p = 0.f;
    for (i = m-1; i >= l; --i){
      f = s*e[i-1];
      b = c*e[i-1];
      slartgf(g, f, c, s, r);
      if (i != m-1) e[i] = r;
      g = d[i] - p;
      r = (d[i-1] - g)*s + 2.f*c*b;
      p = s*r;
      d[i] = g + p;
      g = c*r - b;
      cw[i-l] = c; sw[i-l] = -s;
    }
    for (j = m-l; j >= 1; --j) rot2(z, l+j-2, cw[j-1], sw[j-1]);
    d[l-1] = d[l-1] - p;
    e[l-1] = g;
    goto L40;
L80:
    d[l-1] = p;
    l += 1;
    if (l <= lend) goto L40;
    goto L140;
  } else {
L90:
    if (l != lend){
      for (m = l; m >= lend+1; --m){
        tst = fabsf(e[m-2]); tst = tst*tst;
        if (tst <= (eps2*fabsf(d[m-1]))*fabsf(d[m-2]) + safmin) goto L110;
      }
    }
    m = lend;
L110:
    if (m > lend) e[m-2] = 0.f;
    p = d[l-1];
    if (m == l) goto L130;
    if (m == l-1){
      slaev2f(d[l-2], e[l-2], d[l-1], rt1, rt2, c, s);
      rot2(z, l-2, c, s);
      d[l-2] = rt1; d[l-1] = rt2; e[l-2] = 0.f;
      l -= 2;
      if (l >= lend) goto L90;
      goto L140;
    }
    if (jtot == nmaxit) goto L140;
    jtot++;
    g = (d[l-2] - p)/(2.f*e[l-2]);
    r = slapy2f(g, 1.f);
    g = d[m-1] - p + (e[l-2]/(g + copysignf(r, g)));
    s = 1.f; c = 1.f; p = 0.f;
    for (i = m; i <= l-1; ++i){
      f = s*e[i-1];
      b = c*e[i-1];
      slartgf(g, f, c, s, r);
      if (i != m) e[i-2] = r;
      g = d[i-1] - p;
      r = (d[i] - g)*s + 2.f*c*b;
      p = s*r;
      d[i-1] = g + p;
      g = c*r - b;
      cw[i-m] = c; sw[i-m] = s;
    }
    for (j = 1; j <= l-m; ++j) rot2(z, m+j-2, cw[j-1], sw[j-1]);
    d[l-1] = d[l-1] - p;
    e[l-2] = g;
    goto L90;
L130:
    d[l-1] = p;
    l -= 1;
    if (l >= lend) goto L90;
    goto L140;
  }
L140:
  if (iscale == 1){
    mul = anorm/ssfmax;
    for (i = lsv; i <= lendsv; ++i)   d[i-1] *= mul;
    for (i = lsv; i <= lendsv-1; ++i) e[i-1] *= mul;
  } else if (iscale == 2){
    mul = anorm/ssfmin;
    for (i = lsv; i <= lendsv; ++i)   d[i-1] *= mul;
    for (i = lsv; i <= lendsv-1; ++i) e[i-1] *= mul;
  }
  if (jtot < nmaxit) goto L10;
  return;
L160:
  for (ii = 2; ii <= n; ++ii){
    i = ii - 1; k = i; p = d[i-1];
    for (j = ii; j <= n; ++j){
      if (d[j-1] < p){ k = j; p = d[j-1]; }
    }
    if (k != i){
      d[k-1] = d[i-1]; d[i-1] = p;
      for (j = 0; j < 3; ++j){ float t = z[j][i-1]; z[j][i-1] = z[j][k-1]; z[j][k-1] = t; }
    }
  }
}

__device__ __noinline__ void eigh3_normal(float a11, float a21, float a31,
                                          float a22, float a32, float a33,
                                          float* out3){
#pragma clang fp contract(off)
  float d[3], e[2], z[3][3];
  float tau1 = 0.f, v2 = 0.f;
  float alpha = a21;
  float xnorm = fabsf(a31);
  if (xnorm == 0.f){
    e[0] = alpha;
    tau1 = 0.f;
  } else {
    float beta = -copysignf(slapy2f(alpha, xnorm), alpha);
    tau1 = (beta - alpha)/beta;
    v2 = a31*(1.f/(alpha - beta));
    float x1 = tau1*a22 + tau1*(a32*v2);
    float x2 = tau1*a32 + (tau1*v2)*a33;
    float al = -0.5f*tau1*(x1 + x2*v2);
    float w1 = x1 + al;
    float w2 = x2 + al*v2;
    a22 = a22 - w1 - w1;
    a32 = a32 - v2*w1 - w2;
    a33 = a33 - v2*w2 - w2*v2;
    e[0] = beta;
  }
  e[1] = a32;
  d[0] = a11; d[1] = a22; d[2] = a33;
  ssteqr3(d, e, z);
  if (tau1 != 0.f){
    #pragma unroll
    for (int jj = 0; jj < 3; ++jj){
      float wj  = z[1][jj] + v2*z[2][jj];
      float tmp = tau1*wj;
      z[1][jj] = z[1][jj] - tmp;
      z[2][jj] = z[2][jj] - v2*tmp;
    }
  }
  out3[0] = z[0][0]; out3[1] = z[1][0]; out3[2] = z[2][0];
}

// ---------------- helpers ----------------

__device__ __forceinline__ float sq3f(float x, float y, float z){
#pragma clang fp contract(off)
  return x*x + y*y + z*z;
}

__device__ __forceinline__ float d2f(float qs, float qx, float qy, float qz, float4 c){
#pragma clang fp contract(off)
  float dot = qx*c.x + qy*c.y + qz*c.z;
  return (qs + c.w) - 2.f*dot;
}

// Lex-aware sorted insert: keeps the 16 smallest (d2, idx) pairs in ascending
// lex order. Order-independent (exact top_k semantics incl. index tie-break).
__device__ __forceinline__ void lexInsert16(float dd, int idx, float bd[16], int bidx[16]){
#pragma clang fp contract(off)
  bool en = (dd < bd[15]) || (dd == bd[15] && idx < bidx[15]);
  if (en){
    bd[15] = dd; bidx[15] = idx;
    #pragma unroll
    for (int k = 15; k > 0; --k){
      bool sw = (bd[k] < bd[k-1]) || (bd[k] == bd[k-1] && bidx[k] < bidx[k-1]);
      float td0 = sw ? bd[k]   : bd[k-1];
      float td1 = sw ? bd[k-1] : bd[k];
      int   ti0 = sw ? bidx[k]   : bidx[k-1];
      int   ti1 = sw ? bidx[k-1] : bidx[k];
      bd[k-1] = td0; bd[k] = td1; bidx[k-1] = ti0; bidx[k] = ti1;
    }
  }
}

__device__ __forceinline__ unsigned spread3(unsigned v){
  v &= 1023u;
  v = (v | (v << 16)) & 0x030000FFu;
  v = (v | (v << 8))  & 0x0300F00Fu;
  v = (v | (v << 4))  & 0x030C30C3u;
  v = (v | (v << 2))  & 0x09249249u;
  return v;
}

// ---------------- kernel A: Morton sort + chunk AABBs (8 blocks) ----------------

__global__ __launch_bounds__(1024) void build_kernel(const float* __restrict__ pred,
                                                     const float* __restrict__ gt,
                                                     float4* __restrict__ sortedPts,
                                                     int* __restrict__ origIdx,
                                                     float4* __restrict__ aabbLo,
                                                     float4* __restrict__ aabbHi){
  __shared__ unsigned keys[NPTS];                // 32 KiB
  const int cloud = blockIdx.x;                  // 0..7
  const int grp = cloud >> 2, b = cloud & 3;
  const float* __restrict__ base = (grp ? gt : pred) + (size_t)b*(NPTS*3);
  const int tid = threadIdx.x;

  for (int p = tid; p < NPTS; p += 1024){
    float x = base[p*3+0], y = base[p*3+1], z = base[p*3+2];
    unsigned xu = (unsigned)(int)fminf(fmaxf((x + 4.f)*8.f, 0.f), 63.f);
    unsigned yu = (unsigned)(int)fminf(fmaxf((y + 4.f)*8.f, 0.f), 63.f);
    unsigned zu = (unsigned)(int)fminf(fmaxf((z + 4.f)*8.f, 0.f), 63.f);
    unsigned code = spread3(xu) | (spread3(yu) << 1) | (spread3(zu) << 2);  // 18 bits
    keys[p] = (code << 13) | (unsigned)p;        // 31-bit key, idx tie-break
  }
  __syncthreads();

  for (int k = 2; k <= NPTS; k <<= 1){
    for (int j = k >> 1; j > 0; j >>= 1){
      for (int i = tid; i < NPTS; i += 1024){
        int ixj = i ^ j;
        if (ixj > i){
          unsigned a = keys[i], c = keys[ixj];
          bool up = ((i & k) == 0);
          if ((a > c) == up){ keys[i] = c; keys[ixj] = a; }
        }
      }
      __syncthreads();
    }
  }

  const size_t sb = (size_t)cloud * NPTS;
  for (int p = tid; p < NPTS; p += 1024){
    int orig = (int)(keys[p] & 8191u);
    float x = base[orig*3+0], y = base[orig*3+1], z = base[orig*3+2];
    sortedPts[sb + p] = make_float4(x, y, z, sq3f(x, y, z));
    origIdx[sb + p] = orig;
  }
  __syncthreads();

  for (int c = tid; c < NCHUNK; c += 1024){
    float lx=3e38f, ly=3e38f, lz=3e38f, hx=-3e38f, hy=-3e38f, hz=-3e38f;
    for (int t = 0; t < 16; ++t){
      float4 p = sortedPts[sb + c*16 + t];
      lx = fminf(lx, p.x); ly = fminf(ly, p.y); lz = fminf(lz, p.z);
      hx = fmaxf(hx, p.x); hy = fmaxf(hy, p.y); hz = fmaxf(hz, p.z);
    }
    aabbLo[(size_t)cloud*NCHUNK + c] = make_float4(lx, ly, lz, 0.f);
    aabbHi[(size_t)cloud*NCHUNK + c] = make_float4(hx, hy, hz, 0.f);
  }
}

// ---------------- kernel B: pruned exact KNN + normals (256 blocks) ----------------

__global__ __launch_bounds__(256) void knn_kernel(const float* __restrict__ pred,
                                                  const float* __restrict__ gt,
                                                  const float4* __restrict__ sortedPts,
                                                  const int* __restrict__ origIdx,
                                                  const float4* __restrict__ aabbLo,
                                                  const float4* __restrict__ aabbHi,
                                                  float* __restrict__ normals){
#pragma clang fp contract(off)
  __shared__ float4 sLo[NCHUNK], sHi[NCHUNK];    // 16 KiB
  __shared__ unsigned short slist[4][NCHUNK+16]; // ~4.1 KiB, per-wave survivor list
  __shared__ int scnt[4];
  const int tid = threadIdx.x;
  const int cloud = blockIdx.x >> 5;             // 32 blocks per cloud
  const int grp = cloud >> 2, b = cloud & 3;
  const float* __restrict__ obase = (grp ? gt : pred) + (size_t)b*(NPTS*3);
  const size_t sb = (size_t)cloud * NPTS;

  for (int i = tid; i < NCHUNK; i += 256){
    sLo[i] = aabbLo[(size_t)cloud*NCHUNK + i];
    sHi[i] = aabbHi[(size_t)cloud*NCHUNK + i];
  }
  if (tid < 4) scnt[tid] = 0;
  __syncthreads();

  const int w = tid >> 6, lane = tid & 63;
  const int spos = ((blockIdx.x & 31) << 8) + (w << 6) + lane;  // sorted query pos
  const float4 q = sortedPts[sb + spos];
  const float qx = q.x, qy = q.y, qz = q.z, qs = q.w;

  float bd[16]; int bidx[16];
  #pragma unroll
  for (int j = 0; j < 16; ++j){ bd[j] = 3.0e38f; bidx[j] = 0x7fffffff; }

  // ---- seed: home chunks (guarantees >= 32 candidates incl. self) ----
  const int myc = spos >> 4;
  const int cs0 = max(myc-1, 0), cs1 = min(myc+1, NCHUNK-1);
  for (int c = cs0; c <= cs1; ++c){
    const int b2 = c << 4;
    #pragma unroll 4
    for (int t = 0; t < 16; ++t){
      float4 cd = sortedPts[sb + b2 + t];
      int ci = origIdx[sb + b2 + t];
      float dd = d2f(qs, qx, qy, qz, cd);
      lexInsert16(dd, ci, bd, bidx);
    }
  }
  float thr = bd[15]; int thrI = bidx[15];

  // ---- wave query AABB + wave threshold ----
  float wlx = qx, whx = qx, wly = qy, why = qy, wlz = qz, whz = qz, thrW = thr;
  #pragma unroll
  for (int s = 1; s < 64; s <<= 1){
    wlx = fminf(wlx, __shfl_xor(wlx, s, 64)); whx = fmaxf(whx, __shfl_xor(whx, s, 64));
    wly = fminf(wly, __shfl_xor(wly, s, 64)); why = fmaxf(why, __shfl_xor(why, s, 64));
    wlz = fminf(wlz, __shfl_xor(wlz, s, 64)); whz = fmaxf(whz, __shfl_xor(whz, s, 64));
    thrW = fmaxf(thrW, __shfl_xor(thrW, s, 64));
  }
  thrW += MARGIN;   // covers fp error of d2_ref (~8e-6 abs) + lb rounding

  // ---- wave-level conservative prune: 8 chunks per lane ----
  for (int r = 0; r < 8; ++r){
    int c = (r << 6) + lane;
    float4 lo = sLo[c], hi = sHi[c];
    float dx = fmaxf(fmaxf(lo.x - whx, wlx - hi.x), 0.f);
    float dy = fmaxf(fmaxf(lo.y - why, wly - hi.y), 0.f);
    float dz = fmaxf(fmaxf(lo.z - whz, wlz - hi.z), 0.f);
    float lb = dx*dx + dy*dy + dz*dz;
    if (lb <= thrW){
      int pos = atomicAdd(&scnt[w], 1);
      slist[w][pos] = (unsigned short)c;
    }
  }
  __syncthreads();
  const int n = scnt[w];

  // ---- main scan over surviving chunks, depth-4 lazy buffer, lex-exact ----
  float b0d = 0.f, b1d = 0.f, b2d = 0.f, b3d = 0.f;
  int   b0i = 0,   b1i = 0,   b2i = 0,   b3i = 0,   cnt = 0;

#define FLUSH_BUF() do {                                   \
    if (cnt > 3) lexInsert16(b3d, b3i, bd, bidx);          \
    if (cnt > 2) lexInsert16(b2d, b2i, bd, bidx);          \
    if (cnt > 1) lexInsert16(b1d, b1i, bd, bidx);          \
    if (cnt > 0) lexInsert16(b0d, b0i, bd, bidx);          \
    cnt = 0; thr = bd[15]; thrI = bidx[15];                \
  } while (0)

  for (int i = 0; i < n; ++i){
    const int c = slist[w][i];                   // wave-uniform
    const bool ns = (c < cs0) || (c > cs1);      // skip my seed chunks (dedupe)
    const int b2 = c << 4;
    #pragma unroll 4
    for (int t = 0; t < 16; ++t){
      float4 cd = sortedPts[sb + b2 + t];
      int ci = origIdx[sb + b2 + t];
      float dd = d2f(qs, qx, qy, qz, cd);
      bool pass = ns && ((dd < thr) || (dd == thr && ci < thrI));
      if (__any(pass)){
        b3d = pass ? b2d : b3d;  b3i = pass ? b2i : b3i;
        b2d = pass ? b1d : b2d;  b2i = pass ? b1i : b2i;
        b1d = pass ? b0d : b1d;  b1i = pass ? b0i : b1i;
        b0d = pass ? dd  : b0d;  b0i = pass ? ci  : b0i;
        cnt += (int)pass;
        if (__any(cnt >= 4)) FLUSH_BUF();
      }
    }
  }
  FLUSH_BUF();
#undef FLUSH_BUF

  // ---- gather (orig coords, lex order), covariance, eigh — verbatim r1-5 ----
  float gxx[16], gyy[16], gzz[16];
  #pragma unroll
  for (int r = 0; r < 16; ++r){
    const float* p = obase + (size_t)bidx[r]*3;
    gxx[r] = p[0]; gyy[r] = p[1]; gzz[r] = p[2];
  }
  float mx = 0.f, my = 0.f, mz = 0.f;
  #pragma unroll
  for (int r = 0; r < 16; ++r){ mx += gxx[r]; my += gyy[r]; mz += gzz[r]; }
  mx *= 0.0625f; my *= 0.0625f; mz *= 0.0625f;

  float c00=0.f, c10=0.f, c20=0.f, c11=0.f, c21=0.f, c22=0.f;
  #pragma unroll
  for (int r = 0; r < 16; ++r){
    float cx = gxx[r]-mx, cy = gyy[r]-my, cz = gzz[r]-mz;
    c00 += cx*cx; c10 += cy*cx; c20 += cz*cx;
    c11 += cy*cy; c21 += cz*cy; c22 += cz*cz;
  }
  c00 *= 0.0625f; c10 *= 0.0625f; c20 *= 0.0625f;
  c11 *= 0.0625f; c21 *= 0.0625f; c22 *= 0.0625f;

  float nrm[3];
  eigh3_normal(c00, c10, c20, c11, c21, c22, nrm);

  const int qorig = origIdx[sb + spos];
  float* o = normals + ((size_t)(grp*NB + b)*NPTS + qorig)*3;
  o[0] = nrm[0]; o[1] = nrm[1]; o[2] = nrm[2];
}

// ---------------- loss ----------------

__global__ __launch_bounds__(256) void loss_partial(const float* __restrict__ normals,
                                                    float* __restrict__ partials){
  __shared__ float red[256];
  const float4* a4 = (const float4*)normals;                        // 24576 float4
  const float4* g4 = (const float4*)(normals + (size_t)NB*NPTS*3);
  float acc = 0.f;
  for (int i = blockIdx.x*256 + threadIdx.x; i < 24576; i += 64*256){
    float4 a = a4[i], g = g4[i];
    acc += a.x*g.x + a.y*g.y + a.z*g.z + a.w*g.w;
  }
  red[threadIdx.x] = acc;
  __syncthreads();
  for (int sft = 128; sft > 0; sft >>= 1){
    if (threadIdx.x < sft) red[threadIdx.x] += red[threadIdx.x + sft];
    __syncthreads();
  }
  if (threadIdx.x == 0) partials[blockIdx.x] = red[0];
}

__global__ void loss_final(const float* __restrict__ partials,
                           float* __restrict__ out){
  float v = partials[threadIdx.x];
  #pragma unroll
  for (int s = 32; s > 0; s >>= 1) v += __shfl_down(v, s, 64);
  if (threadIdx.x == 0) out[0] = 1.f - v*(1.f/32768.f);
}

extern "C" void kernel_launch(void* const* d_in, const int* in_sizes, int n_in,
                              void* d_out, int out_size, void* d_ws, size_t ws_size,
                              hipStream_t stream) {
  const float* pred = (const float*)d_in[0];
  const float* gt   = (const float*)d_in[1];
  // workspace layout (floats): normals[196608] | partials[64] | sortedPts
  // (8*8192 float4 = 262144 f) | origIdx (65536 i) | aabbLo/Hi (2*16384 f)
  float*  normals   = (float*)d_ws;
  float*  partials  = normals + (size_t)2*NB*NPTS*3;          // 196608
  float4* sortedPts = (float4*)(partials + 64);               // 16B-aligned (786688 B)
  int*    origIdx   = (int*)(sortedPts + (size_t)8*NPTS);
  float4* aabbLo    = (float4*)(origIdx + (size_t)8*NPTS);    // 16B-aligned (2097408 B)
  float4* aabbHi    = aabbLo + (size_t)8*NCHUNK;
  build_kernel<<<8, 1024, 0, stream>>>(pred, gt, sortedPts, origIdx, aabbLo, aabbHi);
  knn_kernel<<<256, 256, 0, stream>>>(pred, gt, sortedPts, origIdx, aabbLo, aabbHi, normals);
  loss_partial<<<64, 256, 0, stream>>>(normals, partials);
  loss_final<<<1, 64, 0, stream>>>(partials, (float*)d_out);
}

// Round 7
// 2347.634 us; speedup vs baseline: 1.4956x; 1.4956x over previous
//
#include <hip/hip_runtime.h>
#include <math.h>

// NormalConsistencyLoss: B=4, N=8192, D=3, K=16, fp32 in/out (scalar out).
// [pack_kernel] cloud -> float4(x,y,z,sq).
// [knn_normal_kernel] exact 16-NN: 4 threads/query scan contiguous 2048-slices
//   of the packed cloud via wave-uniform (scalar) loads; passing candidates go
//   to a per-lane LDS stack (depth 4); flush does lex-exact insert16. 4-way lex
//   merge == lax.top_k. PCA normal via faithful LAPACK ssyevd(fp32) port.
// [loss_partial/loss_final] 1 - mean(dot).

#define NPTS 8192
#define NB   4

// ---------------- LAPACK single-precision ports (sign-faithful) ----------------

__device__ __forceinline__ float slapy2f(float x, float y){
#pragma clang fp contract(off)
  float xa = fabsf(x), ya = fabsf(y);
  float w = fmaxf(xa, ya), z = fminf(xa, ya);
  if (z == 0.f) return w;
  float t = z / w;
  return w * sqrtf(1.f + t*t);
}

// LAPACK >= 3.10 slartg
__device__ __forceinline__ void slartgf(float f, float g, float& c, float& s, float& r){
#pragma clang fp contract(off)
  const float safmin = 1.17549435e-38f;
  const float safmax = 8.50705917e37f;
  const float rtmin  = 1.08420217e-19f;
  const float rtmax  = 6.52318604e18f;
  if (g == 0.f){ c = 1.f; s = 0.f; r = f; }
  else if (f == 0.f){ c = 0.f; s = copysignf(1.f, g); r = fabsf(g); }
  else {
    float f1 = fabsf(f), g1 = fabsf(g);
    if (f1 > rtmin && f1 < rtmax && g1 > rtmin && g1 < rtmax){
      float d = sqrtf(f*f + g*g);
      c = f1 / d;
      r = copysignf(d, f);
      s = g / r;
    } else {
      float u = fminf(safmax, fmaxf(safmin, fmaxf(f1, g1)));
      float fs = f/u, gs = g/u;
      float d = sqrtf(fs*fs + gs*gs);
      c = fabsf(fs)/d;
      r = copysignf(d, f);
      r = r*u;
      s = g/r;
    }
  }
}

__device__ __forceinline__ void slaev2f(float a, float b, float cc,
                                        float& rt1, float& rt2, float& cs1, float& sn1){
#pragma clang fp contract(off)
  float sm  = a + cc;
  float df  = a - cc;
  float adf = fabsf(df);
  float tb  = b + b;
  float ab  = fabsf(tb);
  float acmx, acmn;
  if (fabsf(a) > fabsf(cc)){ acmx = a; acmn = cc; } else { acmx = cc; acmn = a; }
  float rt;
  if (adf > ab){ float t = ab/adf; rt = adf*sqrtf(1.f + t*t); }
  else if (adf < ab){ float t = adf/ab; rt = ab*sqrtf(1.f + t*t); }
  else rt = ab*sqrtf(2.f);
  int sgn1;
  if (sm < 0.f){ rt1 = 0.5f*(sm - rt); sgn1 = -1; rt2 = (acmx/rt1)*acmn - (b/rt1)*b; }
  else if (sm > 0.f){ rt1 = 0.5f*(sm + rt); sgn1 = 1; rt2 = (acmx/rt1)*acmn - (b/rt1)*b; }
  else { rt1 = 0.5f*rt; rt2 = -0.5f*rt; sgn1 = 1; }
  int sgn2; float cs;
  if (df >= 0.f){ cs = df + rt; sgn2 = 1; } else { cs = df - rt; sgn2 = -1; }
  float acs = fabsf(cs);
  if (acs > ab){ float ct = -tb/cs; sn1 = 1.f/sqrtf(1.f + ct*ct); cs1 = ct*sn1; }
  else {
    if (ab == 0.f){ cs1 = 1.f; sn1 = 0.f; }
    else { float tn = -cs/tb; cs1 = 1.f/sqrtf(1.f + tn*tn); sn1 = tn*cs1; }
  }
  if (sgn1 == sgn2){ float tn = cs1; cs1 = -sn1; sn1 = tn; }
}

__device__ __forceinline__ void rot2(float z[3][3], int ja, float c, float s){
#pragma clang fp contract(off)
  #pragma unroll
  for (int i = 0; i < 3; ++i){
    float t1 = z[i][ja+1];
    float t0 = z[i][ja];
    z[i][ja+1] = c*t1 - s*t0;
    z[i][ja]   = s*t1 + c*t0;
  }
}

// Faithful port of LAPACK ssteqr('I', n=3, d, e, z)
__device__ __noinline__ void ssteqr3(float* d, float* e, float z[3][3]){
#pragma clang fp contract(off)
  const float eps    = 5.96046448e-08f;
  const float eps2   = 3.55271368e-15f;
  const float safmin = 1.17549435e-38f;
  const float ssfmax = 3.07445735e+18f;
  const float ssfmin = 3.05175781e-05f;
  const int n = 3;
  float cw[2], sw[2];
  int nmaxit, jtot, l1, l, lsv, lend, lendsv, m, iscale, i, j, ii, k;
  float anorm, p, g, r, c, s, f, b, rt1, rt2, tst, mul;

  for (i = 0; i < 3; ++i) for (j = 0; j < 3; ++j) z[i][j] = (i == j) ? 1.f : 0.f;
  nmaxit = n*30; jtot = 0; l1 = 1; m = 0; iscale = 0; anorm = 0.f;
  lsv = 1; lendsv = 1; lend = 1; l = 1;

L10:
  if (l1 > n) goto L160;
  if (l1 > 1) e[l1-2] = 0.f;
  if (l1 <= n-1){
    for (m = l1; m <= n-1; ++m){
      tst = fabsf(e[m-1]);
      if (tst == 0.f) goto L30;
      if (tst <= (sqrtf(fabsf(d[m-1]))*sqrtf(fabsf(d[m])))*eps){ e[m-1] = 0.f; goto L30; }
    }
  }
  m = n;
L30:
  l = l1; lsv = l; lend = m; lendsv = lend; l1 = m + 1;
  if (lend == l) goto L10;
  anorm = 0.f;
  for (i = l; i <= lend; ++i)   anorm = fmaxf(anorm, fabsf(d[i-1]));
  for (i = l; i <= lend-1; ++i) anorm = fmaxf(anorm, fabsf(e[i-1]));
  iscale = 0;
  if (anorm == 0.f) goto L10;
  if (anorm > ssfmax){
    iscale = 1; mul = ssfmax/anorm;
    for (i = l; i <= lend; ++i)   d[i-1] *= mul;
    for (i = l; i <= lend-1; ++i) e[i-1] *= mul;
  } else if (anorm < ssfmin){
    iscale = 2; mul = ssfmin/anorm;
    for (i = l; i <= lend; ++i)   d[i-1] *= mul;
    for (i = l; i <= lend-1; ++i) e[i-1] *= mul;
  }
  if (fabsf(d[lend-1]) < fabsf(d[l-1])){ lend = lsv; l = lendsv; }

  if (lend > l){
L40:
    if (l != lend){
      for (m = l; m <= lend-1; ++m){
        tst = fabsf(e[m-1]); tst = tst*tst;
        if (tst <= (eps2*fabsf(d[m-1]))*fabsf(d[m]) + safmin) goto L60;
      }
    }
    m = lend;
L60:
    if (m < lend) e[m-1] = 0.f;
    p = d[l-1];
    if (m == l) goto L80;
    if (m == l+1){
      slaev2f(d[l-1], e[l-1], d[l], rt1, rt2, c, s);
      rot2(z, l-1, c, s);
      d[l-1] = rt1; d[l] = rt2; e[l-1] = 0.f;
      l += 2;
      if (l <= lend) goto L40;
      goto L140;
    }
    if (jtot == nmaxit) goto L140;
    jtot++;
    g = (d[l] - p)/(2.f*e[l-1]);
    r = slapy2f(g, 1.f);
    g = d[m-1] - p + (e[l-1]/(g + copysignf(r, g)));
    s = 1.f; c = 1.f; p = 0.f;
    for (i = m-1; i >= l; --i){
      f = s*e[i-1];
      b = c*e[i-1];
      slartgf(g, f, c, s, r);
      if (i != m-1) e[i] = r;
      g = d[i] - p;
      r = (d[i-1] - g)*s + 2.f*c*b;
      p = s*r;
      d[i] = g + p;
      g = c*r - b;
      cw[i-l] = c; sw[i-l] = -s;
    }
    for (j = m-l; j >= 1; --j) rot2(z, l+j-2, cw[j-1], sw[j-1]);
    d[l-1] = d[l-1] - p;
    e[l-1] = g;
    goto L40;
L80:
    d[l-1] = p;
    l += 1;
    if (l <= lend) goto L40;
    goto L140;
  } else {
L90:
    if (l != lend){
      for (m = l; m >= lend+1; --m){
        tst = fabsf(e[m-2]); tst = tst*tst;
        if (tst <= (eps2*fabsf(d[m-1]))*fabsf(d[m-2]) + safmin) goto L110;
      }
    }
    m = lend;
L110:
    if (m > lend) e[m-2] = 0.f;
    p = d[l-1];
    if (m == l) goto L130;
    if (m == l-1){
      slaev2f(d[l-2], e[l-2], d[l-1], rt1, rt2, c, s);
      rot2(z, l-2, c, s);
      d[l-2] = rt1; d[l-1] = rt2; e[l-2] = 0.f;
      l -= 2;
      if (l >= lend) goto L90;
      goto L140;
    }
    if (jtot == nmaxit) goto L140;
    jtot++;
    g = (d[l-2] - p)/(2.f*e[l-2]);
    r = slapy2f(g, 1.f);
    g = d[m-1] - p + (e[l-2]/(g + copysignf(r, g)));
    s = 1.f; c = 1.f; p = 0.f;
    for (i = m; i <= l-1; ++i){
      f = s*e[i-1];
      b = c*e[i-1];
      slartgf(g, f, c, s, r);
      if (i != m) e[i-2] = r;
      g = d[i-1] - p;
      r = (d[i] - g)*s + 2.f*c*b;
      p = s*r;
      d[i-1] = g + p;
      g = c*r - b;
      cw[i-m] = c; sw[i-m] = s;
    }
    for (j = 1; j <= l-m; ++j) rot2(z, m+j-2, cw[j-1], sw[j-1]);
    d[l-1] = d[l-1] - p;
    e[l-2] = g;
    goto L90;
L130:
    d[l-1] = p;
    l -= 1;
    if (l >= lend) goto L90;
    goto L140;
  }
L140:
  if (iscale == 1){
    mul = anorm/ssfmax;
    for (i = lsv; i <= lendsv; ++i)   d[i-1] *= mul;
    for (i = lsv; i <= lendsv-1; ++i) e[i-1] *= mul;
  } else if (iscale == 2){
    mul = anorm/ssfmin;
    for (i = lsv; i <= lendsv; ++i)   d[i-1] *= mul;
    for (i = lsv; i <= lendsv-1; ++i) e[i-1] *= mul;
  }
  if (jtot < nmaxit) goto L10;
  return;
L160:
  for (ii = 2; ii <= n; ++ii){
    i = ii - 1; k = i; p = d[i-1];
    for (j = ii; j <= n; ++j){
      if (d[j-1] < p){ k = j; p = d[j-1]; }
    }
    if (k != i){
      d[k-1] = d[i-1]; d[i-1] = p;
      for (j = 0; j < 3; ++j){ float t = z[j][i-1]; z[j][i-1] = z[j][k-1]; z[j][k-1] = t; }
    }
  }
}

__device__ __noinline__ void eigh3_normal(float a11, float a21, float a31,
                                          float a22, float a32, float a33,
                                          float* out3){
#pragma clang fp contract(off)
  float d[3], e[2], z[3][3];
  float tau1 = 0.f, v2 = 0.f;
  float alpha = a21;
  float xnorm = fabsf(a31);
  if (xnorm == 0.f){
    e[0] = alpha;
    tau1 = 0.f;
  } else {
    float beta = -copysignf(slapy2f(alpha, xnorm), alpha);
    tau1 = (beta - alpha)/beta;
    v2 = a31*(1.f/(alpha - beta));
    float x1 = tau1*a22 + tau1*(a32*v2);
    float x2 = tau1*a32 + (tau1*v2)*a33;
    float al = -0.5f*tau1*(x1 + x2*v2);
    float w1 = x1 + al;
    float w2 = x2 + al*v2;
    a22 = a22 - w1 - w1;
    a32 = a32 - v2*w1 - w2;
    a33 = a33 - v2*w2 - w2*v2;
    e[0] = beta;
  }
  e[1] = a32;
  d[0] = a11; d[1] = a22; d[2] = a33;
  ssteqr3(d, e, z);
  if (tau1 != 0.f){
    #pragma unroll
    for (int jj = 0; jj < 3; ++jj){
      float wj  = z[1][jj] + v2*z[2][jj];
      float tmp = tau1*wj;
      z[1][jj] = z[1][jj] - tmp;
      z[2][jj] = z[2][jj] - v2*tmp;
    }
  }
  out3[0] = z[0][0]; out3[1] = z[1][0]; out3[2] = z[2][0];
}

// ---------------- helpers ----------------

__device__ __forceinline__ float sq3f(float x, float y, float z){
#pragma clang fp contract(off)
  return x*x + y*y + z*z;
}

__device__ __forceinline__ float d2f(float qs, float qx, float qy, float qz, float4 c){
#pragma clang fp contract(off)
  float dot = qx*c.x + qy*c.y + qz*c.z;
  return (qs + c.w) - 2.f*dot;
}

// Lex-aware sorted insert: keeps the 16 smallest (d2, idx) pairs in ascending
// lex order — order-independent (exact lax.top_k semantics incl. tie-break).
__device__ __forceinline__ void lexInsert16(float dd, int idx, float bd[16], int bidx[16]){
#pragma clang fp contract(off)
  bool en = (dd < bd[15]) || (dd == bd[15] && idx < bidx[15]);
  if (en){
    bd[15] = dd; bidx[15] = idx;
    #pragma unroll
    for (int k = 15; k > 0; --k){
      bool sw = (bd[k] < bd[k-1]) || (bd[k] == bd[k-1] && bidx[k] < bidx[k-1]);
      float td0 = sw ? bd[k]   : bd[k-1];
      float td1 = sw ? bd[k-1] : bd[k];
      int   ti0 = sw ? bidx[k]   : bidx[k-1];
      int   ti1 = sw ? bidx[k-1] : bidx[k];
      bd[k-1] = td0; bd[k] = td1; bidx[k-1] = ti0; bidx[k] = ti1;
    }
  }
}

// ---------------- kernels ----------------

// Pack clouds as float4(x,y,z,sq). 65536 points total.
__global__ __launch_bounds__(256) void pack_kernel(const float* __restrict__ pred,
                                                   const float* __restrict__ gt,
                                                   float4* __restrict__ packed){
#pragma clang fp contract(off)
  int i = blockIdx.x*256 + threadIdx.x;        // 0..65535
  int cloud = i >> 13;                         // 0..7 (0-3 pred, 4-7 gt)
  int p = i & 8191;
  const float* base = ((cloud >> 2) ? gt : pred) + (size_t)(cloud & 3)*(NPTS*3);
  float x = base[p*3+0], y = base[p*3+1], z = base[p*3+2];
  packed[i] = make_float4(x, y, z, sq3f(x, y, z));
}

// grid 1024 x 256. Block: 64 queries of one cloud; 4 threads/query (wave h
// scans contiguous slice [h*2048,(h+1)*2048) of the packed cloud with
// wave-uniform loads). Pass filter dd<=thr (stale-threshold superset, safe);
// passing candidates -> per-lane LDS stack depth 4; flush = lex-exact insert.
// Exact 4-way lex merge == lax.top_k.
__global__ __launch_bounds__(256) void knn_normal_kernel(const float4* __restrict__ packed,
                                                         float* __restrict__ normals){
#pragma clang fp contract(off)
  __shared__ float2 mbuf[4096];                // 32 KiB (merge)
  __shared__ uint2  stk[1024];                 // 8 KiB: [slot][tid]
  const int tid   = threadIdx.x;
  const int bid   = blockIdx.x;
  const int cloud2 = bid >> 9;                 // 0 = pred, 1 = gt
  const int wi    = bid & 511;
  const int b     = wi >> 7;
  const int seg   = wi & 127;
  const int pc    = cloud2*NB + b;             // packed cloud index
  const float4* __restrict__ cp = packed + (size_t)pc*NPTS;
  const int lane = tid & 63;
  const int h    = tid >> 6;
  const int qi   = seg*64 + lane;
  const float4 q = cp[qi];
  const float qx = q.x, qy = q.y, qz = q.z, qs = q.w;

  float bd[16]; int bidx[16];
  #pragma unroll
  for (int j = 0; j < 16; ++j){ bd[j] = 3.0e38f; bidx[j] = 0x7fffffff; }

  float thr = 3.0e38f;
  int cnt = 0;
  const int j0 = h*2048;
  const float4* __restrict__ sp = cp + j0;

#define FLUSH_STACK() do {                                          \
    if (cnt > 0){ uint2 e0 = stk[tid];        lexInsert16(__uint_as_float(e0.x), (int)e0.y, bd, bidx); } \
    if (cnt > 1){ uint2 e1 = stk[256 + tid];  lexInsert16(__uint_as_float(e1.x), (int)e1.y, bd, bidx); } \
    if (cnt > 2){ uint2 e2 = stk[512 + tid];  lexInsert16(__uint_as_float(e2.x), (int)e2.y, bd, bidx); } \
    if (cnt > 3){ uint2 e3 = stk[768 + tid];  lexInsert16(__uint_as_float(e3.x), (int)e3.y, bd, bidx); } \
    cnt = 0; thr = bd[15];                                          \
  } while (0)

  #pragma unroll 4
  for (int j = 0; j < 2048; ++j){
    float4 cd = sp[j];                         // wave-uniform -> scalar load
    float dd = d2f(qs, qx, qy, qz, cd);        // exact reference-order value
    bool pass = dd <= thr;                     // <=: keeps tie candidates (superset)
    if (pass) stk[cnt*256 + tid] = make_uint2(__float_as_uint(dd), (unsigned)(j0 + j));
    cnt += pass ? 1 : 0;
    if (__any(cnt >= 4)) FLUSH_STACK();        // ~25x per wave
  }
  FLUSH_STACK();
#undef FLUSH_STACK

  // ---- exact 4-way lex merge via LDS (entry-major: mbuf[r*256+tid]) ----
  __syncthreads();
  #pragma unroll
  for (int r = 0; r < 16; ++r)
    mbuf[r*256 + tid] = make_float2(bd[r], __int_as_float(bidx[r]));
  __syncthreads();

  if (h == 0){
    int p0 = 0, p1 = 0, p2 = 0, p3 = 0;
    int nidx[16];
    #pragma unroll
    for (int r = 0; r < 16; ++r){
      float bestd; int besti; int bl;
      float dl; int il; bool better;
      if (p0 < 16){ float2 e = mbuf[p0*256 + lane]; bestd = e.x; besti = __float_as_int(e.y); }
      else { bestd = 3.4e38f; besti = 0x7fffffff; }
      bl = 0;
      if (p1 < 16){ float2 e = mbuf[p1*256 + 64 + lane]; dl = e.x; il = __float_as_int(e.y); }
      else { dl = 3.4e38f; il = 0x7fffffff; }
      better = (dl < bestd) || (dl == bestd && il < besti);
      if (better){ bestd = dl; besti = il; bl = 1; }
      if (p2 < 16){ float2 e = mbuf[p2*256 + 128 + lane]; dl = e.x; il = __float_as_int(e.y); }
      else { dl = 3.4e38f; il = 0x7fffffff; }
      better = (dl < bestd) || (dl == bestd && il < besti);
      if (better){ bestd = dl; besti = il; bl = 2; }
      if (p3 < 16){ float2 e = mbuf[p3*256 + 192 + lane]; dl = e.x; il = __float_as_int(e.y); }
      else { dl = 3.4e38f; il = 0x7fffffff; }
      better = (dl < bestd) || (dl == bestd && il < besti);
      if (better){ bestd = dl; besti = il; bl = 3; }
      nidx[r] = besti;
      p0 += (bl == 0); p1 += (bl == 1); p2 += (bl == 2); p3 += (bl == 3);
    }

    // gather neighbors (packed coords == original bits), covariance, eigh
    float gxx[16], gyy[16], gzz[16];
    #pragma unroll
    for (int r = 0; r < 16; ++r){
      float4 p = cp[nidx[r]];
      gxx[r] = p.x; gyy[r] = p.y; gzz[r] = p.z;
    }
    float mx = 0.f, my = 0.f, mz = 0.f;
    #pragma unroll
    for (int r = 0; r < 16; ++r){ mx += gxx[r]; my += gyy[r]; mz += gzz[r]; }
    mx *= 0.0625f; my *= 0.0625f; mz *= 0.0625f;

    float c00=0.f, c10=0.f, c20=0.f, c11=0.f, c21=0.f, c22=0.f;
    #pragma unroll
    for (int r = 0; r < 16; ++r){
      float cx = gxx[r]-mx, cy = gyy[r]-my, cz = gzz[r]-mz;
      c00 += cx*cx; c10 += cy*cx; c20 += cz*cx;
      c11 += cy*cy; c21 += cz*cy; c22 += cz*cz;
    }
    c00 *= 0.0625f; c10 *= 0.0625f; c20 *= 0.0625f;
    c11 *= 0.0625f; c21 *= 0.0625f; c22 *= 0.0625f;

    float nrm[3];
    eigh3_normal(c00, c10, c20, c11, c21, c22, nrm);

    float* o = normals + ((size_t)pc*NPTS + qi)*3;
    o[0] = nrm[0]; o[1] = nrm[1]; o[2] = nrm[2];
  }
}

// ---------------- loss ----------------

__global__ __launch_bounds__(256) void loss_partial(const float* __restrict__ normals,
                                                    float* __restrict__ partials){
  __shared__ float red[256];
  const float4* a4 = (const float4*)normals;                        // 24576 float4
  const float4* g4 = (const float4*)(normals + (size_t)NB*NPTS*3);
  float acc = 0.f;
  for (int i = blockIdx.x*256 + threadIdx.x; i < 24576; i += 64*256){
    float4 a = a4[i], g = g4[i];
    acc += a.x*g.x + a.y*g.y + a.z*g.z + a.w*g.w;
  }
  red[threadIdx.x] = acc;
  __syncthreads();
  for (int sft = 128; sft > 0; sft >>= 1){
    if (threadIdx.x < sft) red[threadIdx.x] += red[threadIdx.x + sft];
    __syncthreads();
  }
  if (threadIdx.x == 0) partials[blockIdx.x] = red[0];
}

__global__ void loss_final(const float* __restrict__ partials,
                           float* __restrict__ out){
  float v = partials[threadIdx.x];
  #pragma unroll
  for (int s = 32; s > 0; s >>= 1) v += __shfl_down(v, s, 64);
  if (threadIdx.x == 0) out[0] = 1.f - v*(1.f/32768.f);
}

extern "C" void kernel_launch(void* const* d_in, const int* in_sizes, int n_in,
                              void* d_out, int out_size, void* d_ws, size_t ws_size,
                              hipStream_t stream) {
  const float* pred = (const float*)d_in[0];
  const float* gt   = (const float*)d_in[1];
  // ws layout: normals (196608 f) | partials (64 f) | packed (65536 float4)
  float*  normals  = (float*)d_ws;
  float*  partials = normals + (size_t)2*NB*NPTS*3;
  float4* packed   = (float4*)(partials + 64);        // 16B-aligned (786688 B)
  pack_kernel<<<256, 256, 0, stream>>>(pred, gt, packed);
  knn_normal_kernel<<<1024, 256, 0, stream>>>(packed, normals);
  loss_partial<<<64, 256, 0, stream>>>(normals, partials);
  loss_final<<<1, 64, 0, stream>>>(partials, (float*)d_out);
}

// Round 8
// 631.999 us; speedup vs baseline: 5.5554x; 3.7146x over previous
//
#include <hip/hip_runtime.h>
#include <math.h>

// NormalConsistencyLoss: B=4, N=8192, D=3, K=16, fp32 in/out (scalar out).
// [pack_kernel]   clouds -> float4(x,y,z,sq).
// [select_kernel] exact 16-NN, WAVE-SHARED top-16 (one entry per lane, lanes
//   0-15, ascending lex (d2,idx)). One wave serves 4 queries; per iteration
//   64 lanes compute 64 consecutive candidates (coalesced). Inserts are rare
//   wave events via ballot/ffs/shfl. Bit-identical to lax.top_k.
// [normal_kernel] thread-per-query gather + covariance + faithful LAPACK
//   ssyevd(fp32) port -> normals.
// [loss_partial/loss_final] 1 - mean(dot).

#define NPTS 8192
#define NB   4

// ---------------- LAPACK single-precision ports (sign-faithful) ----------------

__device__ __forceinline__ float slapy2f(float x, float y){
#pragma clang fp contract(off)
  float xa = fabsf(x), ya = fabsf(y);
  float w = fmaxf(xa, ya), z = fminf(xa, ya);
  if (z == 0.f) return w;
  float t = z / w;
  return w * sqrtf(1.f + t*t);
}

// LAPACK >= 3.10 slartg
__device__ __forceinline__ void slartgf(float f, float g, float& c, float& s, float& r){
#pragma clang fp contract(off)
  const float safmin = 1.17549435e-38f;
  const float safmax = 8.50705917e37f;
  const float rtmin  = 1.08420217e-19f;
  const float rtmax  = 6.52318604e18f;
  if (g == 0.f){ c = 1.f; s = 0.f; r = f; }
  else if (f == 0.f){ c = 0.f; s = copysignf(1.f, g); r = fabsf(g); }
  else {
    float f1 = fabsf(f), g1 = fabsf(g);
    if (f1 > rtmin && f1 < rtmax && g1 > rtmin && g1 < rtmax){
      float d = sqrtf(f*f + g*g);
      c = f1 / d;
      r = copysignf(d, f);
      s = g / r;
    } else {
      float u = fminf(safmax, fmaxf(safmin, fmaxf(f1, g1)));
      float fs = f/u, gs = g/u;
      float d = sqrtf(fs*fs + gs*gs);
      c = fabsf(fs)/d;
      r = copysignf(d, f);
      r = r*u;
      s = g/r;
    }
  }
}

__device__ __forceinline__ void slaev2f(float a, float b, float cc,
                                        float& rt1, float& rt2, float& cs1, float& sn1){
#pragma clang fp contract(off)
  float sm  = a + cc;
  float df  = a - cc;
  float adf = fabsf(df);
  float tb  = b + b;
  float ab  = fabsf(tb);
  float acmx, acmn;
  if (fabsf(a) > fabsf(cc)){ acmx = a; acmn = cc; } else { acmx = cc; acmn = a; }
  float rt;
  if (adf > ab){ float t = ab/adf; rt = adf*sqrtf(1.f + t*t); }
  else if (adf < ab){ float t = adf/ab; rt = ab*sqrtf(1.f + t*t); }
  else rt = ab*sqrtf(2.f);
  int sgn1;
  if (sm < 0.f){ rt1 = 0.5f*(sm - rt); sgn1 = -1; rt2 = (acmx/rt1)*acmn - (b/rt1)*b; }
  else if (sm > 0.f){ rt1 = 0.5f*(sm + rt); sgn1 = 1; rt2 = (acmx/rt1)*acmn - (b/rt1)*b; }
  else { rt1 = 0.5f*rt; rt2 = -0.5f*rt; sgn1 = 1; }
  int sgn2; float cs;
  if (df >= 0.f){ cs = df + rt; sgn2 = 1; } else { cs = df - rt; sgn2 = -1; }
  float acs = fabsf(cs);
  if (acs > ab){ float ct = -tb/cs; sn1 = 1.f/sqrtf(1.f + ct*ct); cs1 = ct*sn1; }
  else {
    if (ab == 0.f){ cs1 = 1.f; sn1 = 0.f; }
    else { float tn = -cs/tb; cs1 = 1.f/sqrtf(1.f + tn*tn); sn1 = tn*cs1; }
  }
  if (sgn1 == sgn2){ float tn = cs1; cs1 = -sn1; sn1 = tn; }
}

__device__ __forceinline__ void rot2(float z[3][3], int ja, float c, float s){
#pragma clang fp contract(off)
  #pragma unroll
  for (int i = 0; i < 3; ++i){
    float t1 = z[i][ja+1];
    float t0 = z[i][ja];
    z[i][ja+1] = c*t1 - s*t0;
    z[i][ja]   = s*t1 + c*t0;
  }
}

// Faithful port of LAPACK ssteqr('I', n=3, d, e, z)
__device__ __noinline__ void ssteqr3(float* d, float* e, float z[3][3]){
#pragma clang fp contract(off)
  const float eps    = 5.96046448e-08f;
  const float eps2   = 3.55271368e-15f;
  const float safmin = 1.17549435e-38f;
  const float ssfmax = 3.07445735e+18f;
  const float ssfmin = 3.05175781e-05f;
  const int n = 3;
  float cw[2], sw[2];
  int nmaxit, jtot, l1, l, lsv, lend, lendsv, m, iscale, i, j, ii, k;
  float anorm, p, g, r, c, s, f, b, rt1, rt2, tst, mul;

  for (i = 0; i < 3; ++i) for (j = 0; j < 3; ++j) z[i][j] = (i == j) ? 1.f : 0.f;
  nmaxit = n*30; jtot = 0; l1 = 1; m = 0; iscale = 0; anorm = 0.f;
  lsv = 1; lendsv = 1; lend = 1; l = 1;

L10:
  if (l1 > n) goto L160;
  if (l1 > 1) e[l1-2] = 0.f;
  if (l1 <= n-1){
    for (m = l1; m <= n-1; ++m){
      tst = fabsf(e[m-1]);
      if (tst == 0.f) goto L30;
      if (tst <= (sqrtf(fabsf(d[m-1]))*sqrtf(fabsf(d[m])))*eps){ e[m-1] = 0.f; goto L30; }
    }
  }
  m = n;
L30:
  l = l1; lsv = l; lend = m; lendsv = lend; l1 = m + 1;
  if (lend == l) goto L10;
  anorm = 0.f;
  for (i = l; i <= lend; ++i)   anorm = fmaxf(anorm, fabsf(d[i-1]));
  for (i = l; i <= lend-1; ++i) anorm = fmaxf(anorm, fabsf(e[i-1]));
  iscale = 0;
  if (anorm == 0.f) goto L10;
  if (anorm > ssfmax){
    iscale = 1; mul = ssfmax/anorm;
    for (i = l; i <= lend; ++i)   d[i-1] *= mul;
    for (i = l; i <= lend-1; ++i) e[i-1] *= mul;
  } else if (anorm < ssfmin){
    iscale = 2; mul = ssfmin/anorm;
    for (i = l; i <= lend; ++i)   d[i-1] *= mul;
    for (i = l; i <= lend-1; ++i) e[i-1] *= mul;
  }
  if (fabsf(d[lend-1]) < fabsf(d[l-1])){ lend = lsv; l = lendsv; }

  if (lend > l){
L40:
    if (l != lend){
      for (m = l; m <= lend-1; ++m){
        tst = fabsf(e[m-1]); tst = tst*tst;
        if (tst <= (eps2*fabsf(d[m-1]))*fabsf(d[m]) + safmin) goto L60;
      }
    }
    m = lend;
L60:
    if (m < lend) e[m-1] = 0.f;
    p = d[l-1];
    if (m == l) goto L80;
    if (m == l+1){
      slaev2f(d[l-1], e[l-1], d[l], rt1, rt2, c, s);
      rot2(z, l-1, c, s);
      d[l-1] = rt1; d[l] = rt2; e[l-1] = 0.f;
      l += 2;
      if (l <= lend) goto L40;
      goto L140;
    }
    if (jtot == nmaxit) goto L140;
    jtot++;
    g = (d[l] - p)/(2.f*e[l-1]);
    r = slapy2f(g, 1.f);
    g = d[m-1] - p + (e[l-1]/(g + copysignf(r, g)));
    s = 1.f; c = 1.f; p = 0.f;
    for (i = m-1; i >= l; --i){
      f = s*e[i-1];
      b = c*e[i-1];
      slartgf(g, f, c, s, r);
      if (i != m-1) e[i] = r;
      g = d[i] - p;
      r = (d[i-1] - g)*s + 2.f*c*b;
      p = s*r;
      d[i] = g + p;
      g = c*r - b;
      cw[i-l] = c; sw[i-l] = -s;
    }
    for (j = m-l; j >= 1; --j) rot2(z, l+j-2, cw[j-1], sw[j-1]);
    d[l-1] = d[l-1] - p;
    e[l-1] = g;
    goto L40;
L80:
    d[l-1] = p;
    l += 1;
    if (l <= lend) goto L40;
    goto L140;
  } else {
L90:
    if (l != lend){
      for (m = l; m >= lend+1; --m){
        tst = fabsf(e[m-2]); tst = tst*tst;
        if (tst <= (eps2*fabsf(d[m-1]))*fabsf(d[m-2]) + safmin) goto L110;
      }
    }
    m = lend;
L110:
    if (m > lend) e[m-2] = 0.f;
    p = d[l-1];
    if (m == l) goto L130;
    if (m == l-1){
      slaev2f(d[l-2], e[l-2], d[l-1], rt1, rt2, c, s);
      rot2(z, l-2, c, s);
      d[l-2] = rt1; d[l-1] = rt2; e[l-2] = 0.f;
      l -= 2;
      if (l >= lend) goto L90;
      goto L140;
    }
    if (jtot == nmaxit) goto L140;
    jtot++;
    g = (d[l-2] - p)/(2.f*e[l-2]);
    r = slapy2f(g, 1.f);
    g = d[m-1] - p + (e[l-2]/(g + copysignf(r, g)));
    s = 1.f; c = 1.f; p = 0.f;
    for (i = m; i <= l-1; ++i){
      f = s*e[i-1];
      b = c*e[i-1];
      slartgf(g, f, c, s, r);
      if (i != m) e[i-2] = r;
      g = d[i-1] - p;
      r = (d[i] - g)*s + 2.f*c*b;
      p = s*r;
      d[i-1] = g + p;
      g = c*r - b;
      cw[i-m] = c; sw[i-m] = s;
    }
    for (j = 1; j <= l-m; ++j) rot2(z, m+j-2, cw[j-1], sw[j-1]);
    d[l-1] = d[l-1] - p;
    e[l-2] = g;
    goto L90;
L130:
    d[l-1] = p;
    l -= 1;
    if (l >= lend) goto L90;
    goto L140;
  }
L140:
  if (iscale == 1){
    mul = anorm/ssfmax;
    for (i = lsv; i <= lendsv; ++i)   d[i-1] *= mul;
    for (i = lsv; i <= lendsv-1; ++i) e[i-1] *= mul;
  } else if (iscale == 2){
    mul = anorm/ssfmin;
    for (i = lsv; i <= lendsv; ++i)   d[i-1] *= mul;
    for (i = lsv; i <= lendsv-1; ++i) e[i-1] *= mul;
  }
  if (jtot < nmaxit) goto L10;
  return;
L160:
  for (ii = 2; ii <= n; ++ii){
    i = ii - 1; k = i; p = d[i-1];
    for (j = ii; j <= n; ++j){
      if (d[j-1] < p){ k = j; p = d[j-1]; }
    }
    if (k != i){
      d[k-1] = d[i-1]; d[i-1] = p;
      for (j = 0; j < 3; ++j){ float t = z[j][i-1]; z[j][i-1] = z[j][k-1]; z[j][k-1] = t; }
    }
  }
}

__device__ __noinline__ void eigh3_normal(float a11, float a21, float a31,
                                          float a22, float a32, float a33,
                                          float* out3){
#pragma clang fp contract(off)
  float d[3], e[2], z[3][3];
  float tau1 = 0.f, v2 = 0.f;
  float alpha = a21;
  float xnorm = fabsf(a31);
  if (xnorm == 0.f){
    e[0] = alpha;
    tau1 = 0.f;
  } else {
    float beta = -copysignf(slapy2f(alpha, xnorm), alpha);
    tau1 = (beta - alpha)/beta;
    v2 = a31*(1.f/(alpha - beta));
    float x1 = tau1*a22 + tau1*(a32*v2);
    float x2 = tau1*a32 + (tau1*v2)*a33;
    float al = -0.5f*tau1*(x1 + x2*v2);
    float w1 = x1 + al;
    float w2 = x2 + al*v2;
    a22 = a22 - w1 - w1;
    a32 = a32 - v2*w1 - w2;
    a33 = a33 - v2*w2 - w2*v2;
    e[0] = beta;
  }
  e[1] = a32;
  d[0] = a11; d[1] = a22; d[2] = a33;
  ssteqr3(d, e, z);
  if (tau1 != 0.f){
    #pragma unroll
    for (int jj = 0; jj < 3; ++jj){
      float wj  = z[1][jj] + v2*z[2][jj];
      float tmp = tau1*wj;
      z[1][jj] = z[1][jj] - tmp;
      z[2][jj] = z[2][jj] - v2*tmp;
    }
  }
  out3[0] = z[0][0]; out3[1] = z[1][0]; out3[2] = z[2][0];
}

// ---------------- helpers ----------------

__device__ __forceinline__ float sq3f(float x, float y, float z){
#pragma clang fp contract(off)
  return x*x + y*y + z*z;
}

__device__ __forceinline__ float d2f(float qs, float qx, float qy, float qz, float4 c){
#pragma clang fp contract(off)
  float dot = qx*c.x + qy*c.y + qz*c.z;
  return (qs + c.w) - 2.f*dot;
}

// ---------------- kernels ----------------

// Pack clouds as float4(x,y,z,sq). 65536 points total.
__global__ __launch_bounds__(256) void pack_kernel(const float* __restrict__ pred,
                                                   const float* __restrict__ gt,
                                                   float4* __restrict__ packed){
#pragma clang fp contract(off)
  int i = blockIdx.x*256 + threadIdx.x;        // 0..65535
  int cloud = i >> 13;                         // 0..7 (0-3 pred, 4-7 gt)
  int p = i & 8191;
  const float* base = ((cloud >> 2) ? gt : pred) + (size_t)(cloud & 3)*(NPTS*3);
  float x = base[p*3+0], y = base[p*3+1], z = base[p*3+2];
  packed[i] = make_float4(x, y, z, sq3f(x, y, z));
}

// One wave = 4 queries. Top-16 list for each query is wave-shared: lanes 0-15
// hold the ascending lex (d2,idx) list. Per iter: 64 lanes load 64 consecutive
// candidates (coalesced). pass lanes processed in idx order via ballot/ffs;
// each insert re-checked vs CURRENT 16th -> exact unique top-16 set + order.
__global__ __launch_bounds__(256) void select_kernel(const float4* __restrict__ packed,
                                                     unsigned short* __restrict__ topk){
#pragma clang fp contract(off)
  const int tid  = threadIdx.x;
  const int lane = tid & 63;
  const int g    = blockIdx.x*4 + (tid >> 6);   // global wave id, 0..16383
  const int qbase = g*4;                        // first of 4 queries
  const int pc   = qbase >> 13;                 // cloud 0..7
  const float4* __restrict__ cp = packed + (size_t)pc*NPTS;
  const int q0 = qbase & 8191;

  float4 qv0 = cp[q0+0], qv1 = cp[q0+1], qv2 = cp[q0+2], qv3 = cp[q0+3];

  // wave-shared lists (valid in lanes 0-15)
  float bd0 = 3.0e38f, bd1 = 3.0e38f, bd2 = 3.0e38f, bd3 = 3.0e38f;
  int   bi0 = 0x7fffffff, bi1 = 0x7fffffff, bi2 = 0x7fffffff, bi3 = 0x7fffffff;
  float thr0 = 3.0e38f, thr1 = 3.0e38f, thr2 = 3.0e38f, thr3 = 3.0e38f;
  int   tI0 = 0x7fffffff, tI1 = 0x7fffffff, tI2 = 0x7fffffff, tI3 = 0x7fffffff;

#define PROC(K) {                                                             \
    unsigned long long m = __ballot(pass##K);                                 \
    while (m){                                                                \
      int s = __ffsll(m) - 1;                                                 \
      m &= m - 1;                                                             \
      float dds = __shfl(dd##K, s);                                           \
      int idxs = bidx + s;                                                    \
      if ((dds < thr##K) || (dds == thr##K && idxs < tI##K)){                 \
        bool less = (bd##K < dds) || (bd##K == dds && bi##K < idxs);          \
        unsigned long long lm = __ballot(less) & 0xFFFFull;                   \
        int pos = __popcll(lm);                                               \
        float bup = __shfl_up(bd##K, 1);                                      \
        int   iup = __shfl_up(bi##K, 1);                                      \
        bool tn = (lane == pos);                                              \
        bool tu = (lane > pos) && (lane < 16);                                \
        bd##K = tn ? dds  : (tu ? bup : bd##K);                               \
        bi##K = tn ? idxs : (tu ? iup : bi##K);                               \
        thr##K = __shfl(bd##K, 15);                                           \
        tI##K  = __shfl(bi##K, 15);                                           \
      }                                                                       \
    }                                                                         \
  }

  for (int it = 0; it < NPTS/64; ++it){
    const int bidx = it*64;
    float4 cd = cp[bidx + lane];                 // coalesced 16B/lane
    float dd0 = d2f(qv0.w, qv0.x, qv0.y, qv0.z, cd);
    float dd1 = d2f(qv1.w, qv1.x, qv1.y, qv1.z, cd);
    float dd2 = d2f(qv2.w, qv2.x, qv2.y, qv2.z, cd);
    float dd3 = d2f(qv3.w, qv3.x, qv3.y, qv3.z, cd);
    const int ci = bidx + lane;
    bool pass0 = (dd0 < thr0) || (dd0 == thr0 && ci < tI0);
    bool pass1 = (dd1 < thr1) || (dd1 == thr1 && ci < tI1);
    bool pass2 = (dd2 < thr2) || (dd2 == thr2 && ci < tI2);
    bool pass3 = (dd3 < thr3) || (dd3 == thr3 && ci < tI3);
    PROC(0) PROC(1) PROC(2) PROC(3)
  }
#undef PROC

  if (lane < 16){
    topk[(size_t)(qbase+0)*16 + lane] = (unsigned short)bi0;
    topk[(size_t)(qbase+1)*16 + lane] = (unsigned short)bi1;
    topk[(size_t)(qbase+2)*16 + lane] = (unsigned short)bi2;
    topk[(size_t)(qbase+3)*16 + lane] = (unsigned short)bi3;
  }
}

// Thread per query: gather 16 neighbors (top_k order), covariance, eigh.
__global__ __launch_bounds__(256) void normal_kernel(const float4* __restrict__ packed,
                                                     const unsigned short* __restrict__ topk,
                                                     float* __restrict__ normals){
#pragma clang fp contract(off)
  const int gq = blockIdx.x*256 + threadIdx.x;   // 0..65535
  const int pc = gq >> 13;
  const float4* __restrict__ cp = packed + (size_t)pc*NPTS;
  const unsigned short* __restrict__ tk = topk + (size_t)gq*16;

  float gxx[16], gyy[16], gzz[16];
  #pragma unroll
  for (int r = 0; r < 16; ++r){
    float4 p = cp[tk[r]];
    gxx[r] = p.x; gyy[r] = p.y; gzz[r] = p.z;
  }
  float mx = 0.f, my = 0.f, mz = 0.f;
  #pragma unroll
  for (int r = 0; r < 16; ++r){ mx += gxx[r]; my += gyy[r]; mz += gzz[r]; }
  mx *= 0.0625f; my *= 0.0625f; mz *= 0.0625f;

  float c00=0.f, c10=0.f, c20=0.f, c11=0.f, c21=0.f, c22=0.f;
  #pragma unroll
  for (int r = 0; r < 16; ++r){
    float cx = gxx[r]-mx, cy = gyy[r]-my, cz = gzz[r]-mz;
    c00 += cx*cx; c10 += cy*cx; c20 += cz*cx;
    c11 += cy*cy; c21 += cz*cy; c22 += cz*cz;
  }
  c00 *= 0.0625f; c10 *= 0.0625f; c20 *= 0.0625f;
  c11 *= 0.0625f; c21 *= 0.0625f; c22 *= 0.0625f;

  float nrm[3];
  eigh3_normal(c00, c10, c20, c11, c21, c22, nrm);

  float* o = normals + (size_t)gq*3;
  o[0] = nrm[0]; o[1] = nrm[1]; o[2] = nrm[2];
}

// ---------------- loss ----------------

__global__ __launch_bounds__(256) void loss_partial(const float* __restrict__ normals,
                                                    float* __restrict__ partials){
  __shared__ float red[256];
  const float4* a4 = (const float4*)normals;                        // 24576 float4
  const float4* g4 = (const float4*)(normals + (size_t)NB*NPTS*3);
  float acc = 0.f;
  for (int i = blockIdx.x*256 + threadIdx.x; i < 24576; i += 64*256){
    float4 a = a4[i], g = g4[i];
    acc += a.x*g.x + a.y*g.y + a.z*g.z + a.w*g.w;
  }
  red[threadIdx.x] = acc;
  __syncthreads();
  for (int sft = 128; sft > 0; sft >>= 1){
    if (threadIdx.x < sft) red[threadIdx.x] += red[threadIdx.x + sft];
    __syncthreads();
  }
  if (threadIdx.x == 0) partials[blockIdx.x] = red[0];
}

__global__ void loss_final(const float* __restrict__ partials,
                           float* __restrict__ out){
  float v = partials[threadIdx.x];
  #pragma unroll
  for (int s = 32; s > 0; s >>= 1) v += __shfl_down(v, s, 64);
  if (threadIdx.x == 0) out[0] = 1.f - v*(1.f/32768.f);
}

extern "C" void kernel_launch(void* const* d_in, const int* in_sizes, int n_in,
                              void* d_out, int out_size, void* d_ws, size_t ws_size,
                              hipStream_t stream) {
  const float* pred = (const float*)d_in[0];
  const float* gt   = (const float*)d_in[1];
  // ws (floats): normals 196608 | partials 64 | packed 65536 float4 | topk 1M ushort
  float*          normals  = (float*)d_ws;
  float*          partials = normals + (size_t)2*NB*NPTS*3;
  float4*         packed   = (float4*)(partials + 64);        // 16B-aligned
  unsigned short* topk     = (unsigned short*)(packed + (size_t)8*NPTS);
  pack_kernel  <<<256,   256, 0, stream>>>(pred, gt, packed);
  select_kernel<<<4096,  256, 0, stream>>>(packed, topk);
  normal_kernel<<<256,   256, 0, stream>>>(packed, topk, normals);
  loss_partial <<<64,    256, 0, stream>>>(normals, partials);
  loss_final   <<<1,      64, 0, stream>>>(partials, (float*)d_out);
}

// Round 9
// 571.911 us; speedup vs baseline: 6.1391x; 1.1051x over previous
//
#include <hip/hip_runtime.h>
#include <math.h>

// NormalConsistencyLoss: B=4, N=8192, D=3, K=16, fp32 in/out (scalar out).
// [pack_kernel]   clouds -> float4(x,y,z,sq).
// [select_kernel] exact 16-NN: analytic density threshold (validated by exact
//   count, redo loop w/ measured correction, serial full-scan fallback) ->
//   batch-parallel LDS collection (ballot-prefix append) -> exact wave-shared
//   lex (d2,idx) top-16 finish. Bit-identical to lax.top_k.
// [normal_kernel] thread-per-query covariance + faithful LAPACK ssyevd port.
// [loss_partial/loss_final] 1 - mean(dot).

#define NPTS 8192
#define NB   4
#define CAP  128

// ---------------- LAPACK single-precision ports (sign-faithful) ----------------

__device__ __forceinline__ float slapy2f(float x, float y){
#pragma clang fp contract(off)
  float xa = fabsf(x), ya = fabsf(y);
  float w = fmaxf(xa, ya), z = fminf(xa, ya);
  if (z == 0.f) return w;
  float t = z / w;
  return w * sqrtf(1.f + t*t);
}

// LAPACK >= 3.10 slartg
__device__ __forceinline__ void slartgf(float f, float g, float& c, float& s, float& r){
#pragma clang fp contract(off)
  const float safmin = 1.17549435e-38f;
  const float safmax = 8.50705917e37f;
  const float rtmin  = 1.08420217e-19f;
  const float rtmax  = 6.52318604e18f;
  if (g == 0.f){ c = 1.f; s = 0.f; r = f; }
  else if (f == 0.f){ c = 0.f; s = copysignf(1.f, g); r = fabsf(g); }
  else {
    float f1 = fabsf(f), g1 = fabsf(g);
    if (f1 > rtmin && f1 < rtmax && g1 > rtmin && g1 < rtmax){
      float d = sqrtf(f*f + g*g);
      c = f1 / d;
      r = copysignf(d, f);
      s = g / r;
    } else {
      float u = fminf(safmax, fmaxf(safmin, fmaxf(f1, g1)));
      float fs = f/u, gs = g/u;
      float d = sqrtf(fs*fs + gs*gs);
      c = fabsf(fs)/d;
      r = copysignf(d, f);
      r = r*u;
      s = g/r;
    }
  }
}

__device__ __forceinline__ void slaev2f(float a, float b, float cc,
                                        float& rt1, float& rt2, float& cs1, float& sn1){
#pragma clang fp contract(off)
  float sm  = a + cc;
  float df  = a - cc;
  float adf = fabsf(df);
  float tb  = b + b;
  float ab  = fabsf(tb);
  float acmx, acmn;
  if (fabsf(a) > fabsf(cc)){ acmx = a; acmn = cc; } else { acmx = cc; acmn = a; }
  float rt;
  if (adf > ab){ float t = ab/adf; rt = adf*sqrtf(1.f + t*t); }
  else if (adf < ab){ float t = adf/ab; rt = ab*sqrtf(1.f + t*t); }
  else rt = ab*sqrtf(2.f);
  int sgn1;
  if (sm < 0.f){ rt1 = 0.5f*(sm - rt); sgn1 = -1; rt2 = (acmx/rt1)*acmn - (b/rt1)*b; }
  else if (sm > 0.f){ rt1 = 0.5f*(sm + rt); sgn1 = 1; rt2 = (acmx/rt1)*acmn - (b/rt1)*b; }
  else { rt1 = 0.5f*rt; rt2 = -0.5f*rt; sgn1 = 1; }
  int sgn2; float cs;
  if (df >= 0.f){ cs = df + rt; sgn2 = 1; } else { cs = df - rt; sgn2 = -1; }
  float acs = fabsf(cs);
  if (acs > ab){ float ct = -tb/cs; sn1 = 1.f/sqrtf(1.f + ct*ct); cs1 = ct*sn1; }
  else {
    if (ab == 0.f){ cs1 = 1.f; sn1 = 0.f; }
    else { float tn = -cs/tb; cs1 = 1.f/sqrtf(1.f + tn*tn); sn1 = tn*cs1; }
  }
  if (sgn1 == sgn2){ float tn = cs1; cs1 = -sn1; sn1 = tn; }
}

__device__ __forceinline__ void rot2(float z[3][3], int ja, float c, float s){
#pragma clang fp contract(off)
  #pragma unroll
  for (int i = 0; i < 3; ++i){
    float t1 = z[i][ja+1];
    float t0 = z[i][ja];
    z[i][ja+1] = c*t1 - s*t0;
    z[i][ja]   = s*t1 + c*t0;
  }
}

// Faithful port of LAPACK ssteqr('I', n=3, d, e, z)
__device__ __noinline__ void ssteqr3(float* d, float* e, float z[3][3]){
#pragma clang fp contract(off)
  const float eps    = 5.96046448e-08f;
  const float eps2   = 3.55271368e-15f;
  const float safmin = 1.17549435e-38f;
  const float ssfmax = 3.07445735e+18f;
  const float ssfmin = 3.05175781e-05f;
  const int n = 3;
  float cw[2], sw[2];
  int nmaxit, jtot, l1, l, lsv, lend, lendsv, m, iscale, i, j, ii, k;
  float anorm, p, g, r, c, s, f, b, rt1, rt2, tst, mul;

  for (i = 0; i < 3; ++i) for (j = 0; j < 3; ++j) z[i][j] = (i == j) ? 1.f : 0.f;
  nmaxit = n*30; jtot = 0; l1 = 1; m = 0; iscale = 0; anorm = 0.f;
  lsv = 1; lendsv = 1; lend = 1; l = 1;

L10:
  if (l1 > n) goto L160;
  if (l1 > 1) e[l1-2] = 0.f;
  if (l1 <= n-1){
    for (m = l1; m <= n-1; ++m){
      tst = fabsf(e[m-1]);
      if (tst == 0.f) goto L30;
      if (tst <= (sqrtf(fabsf(d[m-1]))*sqrtf(fabsf(d[m])))*eps){ e[m-1] = 0.f; goto L30; }
    }
  }
  m = n;
L30:
  l = l1; lsv = l; lend = m; lendsv = lend; l1 = m + 1;
  if (lend == l) goto L10;
  anorm = 0.f;
  for (i = l; i <= lend; ++i)   anorm = fmaxf(anorm, fabsf(d[i-1]));
  for (i = l; i <= lend-1; ++i) anorm = fmaxf(anorm, fabsf(e[i-1]));
  iscale = 0;
  if (anorm == 0.f) goto L10;
  if (anorm > ssfmax){
    iscale = 1; mul = ssfmax/anorm;
    for (i = l; i <= lend; ++i)   d[i-1] *= mul;
    for (i = l; i <= lend-1; ++i) e[i-1] *= mul;
  } else if (anorm < ssfmin){
    iscale = 2; mul = ssfmin/anorm;
    for (i = l; i <= lend; ++i)   d[i-1] *= mul;
    for (i = l; i <= lend-1; ++i) e[i-1] *= mul;
  }
  if (fabsf(d[lend-1]) < fabsf(d[l-1])){ lend = lsv; l = lendsv; }

  if (lend > l){
L40:
    if (l != lend){
      for (m = l; m <= lend-1; ++m){
        tst = fabsf(e[m-1]); tst = tst*tst;
        if (tst <= (eps2*fabsf(d[m-1]))*fabsf(d[m]) + safmin) goto L60;
      }
    }
    m = lend;
L60:
    if (m < lend) e[m-1] = 0.f;
    p = d[l-1];
    if (m == l) goto L80;
    if (m == l+1){
      slaev2f(d[l-1], e[l-1], d[l], rt1, rt2, c, s);
      rot2(z, l-1, c, s);
      d[l-1] = rt1; d[l] = rt2; e[l-1] = 0.f;
      l += 2;
      if (l <= lend) goto L40;
      goto L140;
    }
    if (jtot == nmaxit) goto L140;
    jtot++;
    g = (d[l] - p)/(2.f*e[l-1]);
    r = slapy2f(g, 1.f);
    g = d[m-1] - p + (e[l-1]/(g + copysignf(r, g)));
    s = 1.f; c = 1.f; p = 0.f;
    for (i = m-1; i >= l; --i){
      f = s*e[i-1];
      b = c*e[i-1];
      slartgf(g, f, c, s, r);
      if (i != m-1) e[i] = r;
      g = d[i] - p;
      r = (d[i-1] - g)*s + 2.f*c*b;
      p = s*r;
      d[i] = g + p;
      g = c*r - b;
      cw[i-l] = c; sw[i-l] = -s;
    }
    for (j = m-l; j >= 1; --j) rot2(z, l+j-2, cw[j-1], sw[j-1]);
    d[l-1] = d[l-1] - p;
    e[l-1] = g;
    goto L40;
L80:
    d[l-1] = p;
    l += 1;
    if (l <= lend) goto L40;
    goto L140;
  } else {
L90:
    if (l != lend){
      for (m = l; m >= lend+1; --m){
        tst = fabsf(e[m-2]); tst = tst*tst;
        if (tst <= (eps2*fabsf(d[m-1]))*fabsf(d[m-2]) + safmin) goto L110;
      }
    }
    m = lend;
L110:
    if (m > lend) e[m-2] = 0.f;
    p = d[l-1];
    if (m == l) goto L130;
    if (m == l-1){
      slaev2f(d[l-2], e[l-2], d[l-1], rt1, rt2, c, s);
      rot2(z, l-2, c, s);
      d[l-2] = rt1; d[l-1] = rt2; e[l-2] = 0.f;
      l -= 2;
      if (l >= lend) goto L90;
      goto L140;
    }
    if (jtot == nmaxit) goto L140;
    jtot++;
    g = (d[l-2] - p)/(2.f*e[l-2]);
    r = slapy2f(g, 1.f);
    g = d[m-1] - p + (e[l-2]/(g + copysignf(r, g)));
    s = 1.f; c = 1.f; p = 0.f;
    for (i = m; i <= l-1; ++i){
      f = s*e[i-1];
      b = c*e[i-1];
      slartgf(g, f, c, s, r);
      if (i != m) e[i-2] = r;
      g = d[i-1] - p;
      r = (d[i] - g)*s + 2.f*c*b;
      p = s*r;
      d[i-1] = g + p;
      g = c*r - b;
      cw[i-m] = c; sw[i-m] = s;
    }
    for (j = 1; j <= l-m; ++j) rot2(z, m+j-2, cw[j-1], sw[j-1]);
    d[l-1] = d[l-1] - p;
    e[l-2] = g;
    goto L90;
L130:
    d[l-1] = p;
    l -= 1;
    if (l >= lend) goto L90;
    goto L140;
  }
L140:
  if (iscale == 1){
    mul = anorm/ssfmax;
    for (i = lsv; i <= lendsv; ++i)   d[i-1] *= mul;
    for (i = lsv; i <= lendsv-1; ++i) e[i-1] *= mul;
  } else if (iscale == 2){
    mul = anorm/ssfmin;
    for (i = lsv; i <= lendsv; ++i)   d[i-1] *= mul;
    for (i = lsv; i <= lendsv-1; ++i) e[i-1] *= mul;
  }
  if (jtot < nmaxit) goto L10;
  return;
L160:
  for (ii = 2; ii <= n; ++ii){
    i = ii - 1; k = i; p = d[i-1];
    for (j = ii; j <= n; ++j){
      if (d[j-1] < p){ k = j; p = d[j-1]; }
    }
    if (k != i){
      d[k-1] = d[i-1]; d[i-1] = p;
      for (j = 0; j < 3; ++j){ float t = z[j][i-1]; z[j][i-1] = z[j][k-1]; z[j][k-1] = t; }
    }
  }
}

__device__ __noinline__ void eigh3_normal(float a11, float a21, float a31,
                                          float a22, float a32, float a33,
                                          float* out3){
#pragma clang fp contract(off)
  float d[3], e[2], z[3][3];
  float tau1 = 0.f, v2 = 0.f;
  float alpha = a21;
  float xnorm = fabsf(a31);
  if (xnorm == 0.f){
    e[0] = alpha;
    tau1 = 0.f;
  } else {
    float beta = -copysignf(slapy2f(alpha, xnorm), alpha);
    tau1 = (beta - alpha)/beta;
    v2 = a31*(1.f/(alpha - beta));
    float x1 = tau1*a22 + tau1*(a32*v2);
    float x2 = tau1*a32 + (tau1*v2)*a33;
    float al = -0.5f*tau1*(x1 + x2*v2);
    float w1 = x1 + al;
    float w2 = x2 + al*v2;
    a22 = a22 - w1 - w1;
    a32 = a32 - v2*w1 - w2;
    a33 = a33 - v2*w2 - w2*v2;
    e[0] = beta;
  }
  e[1] = a32;
  d[0] = a11; d[1] = a22; d[2] = a33;
  ssteqr3(d, e, z);
  if (tau1 != 0.f){
    #pragma unroll
    for (int jj = 0; jj < 3; ++jj){
      float wj  = z[1][jj] + v2*z[2][jj];
      float tmp = tau1*wj;
      z[1][jj] = z[1][jj] - tmp;
      z[2][jj] = z[2][jj] - v2*tmp;
    }
  }
  out3[0] = z[0][0]; out3[1] = z[1][0]; out3[2] = z[2][0];
}

// ---------------- helpers ----------------

__device__ __forceinline__ float sq3f(float x, float y, float z){
#pragma clang fp contract(off)
  return x*x + y*y + z*z;
}

__device__ __forceinline__ float d2f(float qs, float qx, float qy, float qz, float4 c){
#pragma clang fp contract(off)
  float dot = qx*c.x + qy*c.y + qz*c.z;
  return (qs + c.w) - 2.f*dot;
}

// ---------------- kernels ----------------

// Pack clouds as float4(x,y,z,sq). 65536 points total.
__global__ __launch_bounds__(256) void pack_kernel(const float* __restrict__ pred,
                                                   const float* __restrict__ gt,
                                                   float4* __restrict__ packed){
#pragma clang fp contract(off)
  int i = blockIdx.x*256 + threadIdx.x;        // 0..65535
  int cloud = i >> 13;                         // 0..7 (0-3 pred, 4-7 gt)
  int p = i & 8191;
  const float* base = ((cloud >> 2) ? gt : pred) + (size_t)(cloud & 3)*(NPTS*3);
  float x = base[p*3+0], y = base[p*3+1], z = base[p*3+2];
  packed[i] = make_float4(x, y, z, sq3f(x, y, z));
}

// One wave = 4 queries. (1) analytic thr (validated) scan collects all d2<=thr
// into LDS via ballot-prefix append (batch-parallel); attempted count decides
// validity; redo with measured correction; serial full-scan fallback (dead in
// practice) guarantees exactness. (2) finish: wave-shared sorted top-16 (lanes
// 0-15, lex (d2,idx)) built from the <=CAP collected entries.
__global__ __launch_bounds__(256) void select_kernel(const float4* __restrict__ packed,
                                                     unsigned short* __restrict__ topk){
#pragma clang fp contract(off)
  __shared__ uint2 stk[4][4][CAP];               // 16 KiB
  const int tid  = threadIdx.x;
  const int lane = tid & 63;
  const int w    = tid >> 6;
  const int g    = blockIdx.x*4 + w;             // global wave id, 0..16383
  const int qbase = g*4;
  const int pc   = qbase >> 13;                  // cloud 0..7
  const float4* __restrict__ cp = packed + (size_t)pc*NPTS;
  const int q0 = qbase & 8191;
  const unsigned long long lmlt = (1ull << lane) - 1ull;

  float4 qv0 = cp[q0+0], qv1 = cp[q0+1], qv2 = cp[q0+2], qv3 = cp[q0+3];

  // analytic threshold: target lambda=32 for N(0,1)^3 cloud, clamp for tails
  float thrA0 = fminf(0.0599f * __expf(qv0.w * 0.33333334f), 0.8f);
  float thrA1 = fminf(0.0599f * __expf(qv1.w * 0.33333334f), 0.8f);
  float thrA2 = fminf(0.0599f * __expf(qv2.w * 0.33333334f), 0.8f);
  float thrA3 = fminf(0.0599f * __expf(qv3.w * 0.33333334f), 0.8f);
  int  cnt0 = 0, cnt1 = 0, cnt2 = 0, cnt3 = 0;
  bool done0 = false, done1 = false, done2 = false, done3 = false;

#define SCAN_Q(K) {                                                           \
    float dd = d2f(qv##K.w, qv##K.x, qv##K.y, qv##K.z, cd);                   \
    bool p = (!done##K) && (dd <= thrA##K);                                   \
    unsigned long long mm = __ballot(p);                                      \
    if (mm){                                                                  \
      int pos = cnt##K + __popcll(mm & lmlt);                                 \
      if (p && pos < CAP) stk[w][K][pos] = make_uint2(__float_as_uint(dd), (unsigned)ci); \
      cnt##K += __popcll(mm);                                                 \
    }                                                                         \
  }

  for (int round = 0; round < 5; ++round){
    if (done0 && done1 && done2 && done3) break;
    if (!done0) cnt0 = 0;
    if (!done1) cnt1 = 0;
    if (!done2) cnt2 = 0;
    if (!done3) cnt3 = 0;
    #pragma unroll 2
    for (int it = 0; it < NPTS/64; ++it){
      const int ci = it*64 + lane;
      float4 cd = cp[ci];
      SCAN_Q(0) SCAN_Q(1) SCAN_Q(2) SCAN_Q(3)
    }
    // validate / correct (wave-uniform scalar math)
#define CHECK_Q(K) if (!done##K){                                             \
      if (cnt##K >= 16 && cnt##K <= CAP) done##K = true;                      \
      else thrA##K *= __powf(32.0f / (float)max(cnt##K, 1), 0.6666667f);      \
    }
    CHECK_Q(0) CHECK_Q(1) CHECK_Q(2) CHECK_Q(3)
#undef CHECK_Q
  }
#undef SCAN_Q

  // wave-shared top-16 lists (lanes 0-15), ascending lex (d2,idx)
  float bd0 = 3.0e38f, bd1 = 3.0e38f, bd2 = 3.0e38f, bd3 = 3.0e38f;
  int   bi0 = 0x7fffffff, bi1 = 0x7fffffff, bi2 = 0x7fffffff, bi3 = 0x7fffffff;
  float thr0 = 3.0e38f, thr1 = 3.0e38f, thr2 = 3.0e38f, thr3 = 3.0e38f;
  int   tI0 = 0x7fffffff, tI1 = 0x7fffffff, tI2 = 0x7fffffff, tI3 = 0x7fffffff;

#define EV_INSERT(K, ddv, civ, passv) {                                       \
    unsigned long long m = __ballot(passv);                                   \
    while (m){                                                                \
      int s = __ffsll((unsigned long long)m) - 1;                             \
      m &= m - 1;                                                             \
      float dds = __shfl(ddv, s);                                             \
      int idxs = __shfl(civ, s);                                              \
      if ((dds < thr##K) || (dds == thr##K && idxs < tI##K)){                 \
        bool less = (bd##K < dds) || (bd##K == dds && bi##K < idxs);          \
        unsigned long long lm = __ballot(less) & 0xFFFFull;                   \
        int pos = __popcll(lm);                                               \
        float bup = __shfl_up(bd##K, 1);                                      \
        int   iup = __shfl_up(bi##K, 1);                                      \
        bool tn = (lane == pos);                                              \
        bool tu = (lane > pos) && (lane < 16);                                \
        bd##K = tn ? dds  : (tu ? bup : bd##K);                               \
        bi##K = tn ? idxs : (tu ? iup : bi##K);                               \
        thr##K = __shfl(bd##K, 15);                                           \
        tI##K  = __shfl(bi##K, 15);                                           \
      }                                                                       \
    }                                                                         \
  }

  // ultimate fallback (practically dead): serial full scan for undone queries
  if (!(done0 && done1 && done2 && done3)){
    if (!done0) cnt0 = 0;
    if (!done1) cnt1 = 0;
    if (!done2) cnt2 = 0;
    if (!done3) cnt3 = 0;
    for (int it = 0; it < NPTS/64; ++it){
      const int ci = it*64 + lane;
      float4 cd = cp[ci];
      float dd0 = d2f(qv0.w, qv0.x, qv0.y, qv0.z, cd);
      float dd1 = d2f(qv1.w, qv1.x, qv1.y, qv1.z, cd);
      float dd2 = d2f(qv2.w, qv2.x, qv2.y, qv2.z, cd);
      float dd3 = d2f(qv3.w, qv3.x, qv3.y, qv3.z, cd);
      bool p0 = (!done0) && ((dd0 < thr0) || (dd0 == thr0 && ci < tI0));
      bool p1 = (!done1) && ((dd1 < thr1) || (dd1 == thr1 && ci < tI1));
      bool p2 = (!done2) && ((dd2 < thr2) || (dd2 == thr2 && ci < tI2));
      bool p3 = (!done3) && ((dd3 < thr3) || (dd3 == thr3 && ci < tI3));
      EV_INSERT(0, dd0, ci, p0)
      EV_INSERT(1, dd1, ci, p1)
      EV_INSERT(2, dd2, ci, p2)
      EV_INSERT(3, dd3, ci, p3)
    }
  }

  // finish: exact lex top-16 of collected entries (cnt==0 for fallback queries)
#define FINISH_Q(K) {                                                         \
    for (int b0 = 0; b0 < cnt##K; b0 += 64){                                  \
      int pos = b0 + lane;                                                    \
      bool pv = pos < cnt##K;                                                 \
      uint2 e = stk[w][K][pv ? pos : 0];                                      \
      float ddv = __uint_as_float(e.x);                                       \
      int civ = (int)e.y;                                                     \
      EV_INSERT(K, ddv, civ, pv)                                              \
    }                                                                         \
  }
  FINISH_Q(0) FINISH_Q(1) FINISH_Q(2) FINISH_Q(3)
#undef FINISH_Q
#undef EV_INSERT

  if (lane < 16){
    topk[(size_t)(qbase+0)*16 + lane] = (unsigned short)bi0;
    topk[(size_t)(qbase+1)*16 + lane] = (unsigned short)bi1;
    topk[(size_t)(qbase+2)*16 + lane] = (unsigned short)bi2;
    topk[(size_t)(qbase+3)*16 + lane] = (unsigned short)bi3;
  }
}

// Thread per query: gather 16 neighbors (top_k order), covariance, eigh.
__global__ __launch_bounds__(256) void normal_kernel(const float4* __restrict__ packed,
                                                     const unsigned short* __restrict__ topk,
                                                     float* __restrict__ normals){
#pragma clang fp contract(off)
  const int gq = blockIdx.x*256 + threadIdx.x;   // 0..65535
  const int pc = gq >> 13;
  const float4* __restrict__ cp = packed + (size_t)pc*NPTS;
  const unsigned short* __restrict__ tk = topk + (size_t)gq*16;

  float gxx[16], gyy[16], gzz[16];
  #pragma unroll
  for (int r = 0; r < 16; ++r){
    float4 p = cp[tk[r]];
    gxx[r] = p.x; gyy[r] = p.y; gzz[r] = p.z;
  }
  float mx = 0.f, my = 0.f, mz = 0.f;
  #pragma unroll
  for (int r = 0; r < 16; ++r){ mx += gxx[r]; my += gyy[r]; mz += gzz[r]; }
  mx *= 0.0625f; my *= 0.0625f; mz *= 0.0625f;

  float c00=0.f, c10=0.f, c20=0.f, c11=0.f, c21=0.f, c22=0.f;
  #pragma unroll
  for (int r = 0; r < 16; ++r){
    float cx = gxx[r]-mx, cy = gyy[r]-my, cz = gzz[r]-mz;
    c00 += cx*cx; c10 += cy*cx; c20 += cz*cx;
    c11 += cy*cy; c21 += cz*cy; c22 += cz*cz;
  }
  c00 *= 0.0625f; c10 *= 0.0625f; c20 *= 0.0625f;
  c11 *= 0.0625f; c21 *= 0.0625f; c22 *= 0.0625f;

  float nrm[3];
  eigh3_normal(c00, c10, c20, c11, c21, c22, nrm);

  float* o = normals + (size_t)gq*3;
  o[0] = nrm[0]; o[1] = nrm[1]; o[2] = nrm[2];
}

// ---------------- loss ----------------

__global__ __launch_bounds__(256) void loss_partial(const float* __restrict__ normals,
                                                    float* __restrict__ partials){
  __shared__ float red[256];
  const float4* a4 = (const float4*)normals;                        // 24576 float4
  const float4* g4 = (const float4*)(normals + (size_t)NB*NPTS*3);
  float acc = 0.f;
  for (int i = blockIdx.x*256 + threadIdx.x; i < 24576; i += 64*256){
    float4 a = a4[i], g = g4[i];
    acc += a.x*g.x + a.y*g.y + a.z*g.z + a.w*g.w;
  }
  red[threadIdx.x] = acc;
  __syncthreads();
  for (int sft = 128; sft > 0; sft >>= 1){
    if (threadIdx.x < sft) red[threadIdx.x] += red[threadIdx.x + sft];
    __syncthreads();
  }
  if (threadIdx.x == 0) partials[blockIdx.x] = red[0];
}

__global__ void loss_final(const float* __restrict__ partials,
                           float* __restrict__ out){
  float v = partials[threadIdx.x];
  #pragma unroll
  for (int s = 32; s > 0; s >>= 1) v += __shfl_down(v, s, 64);
  if (threadIdx.x == 0) out[0] = 1.f - v*(1.f/32768.f);
}

extern "C" void kernel_launch(void* const* d_in, const int* in_sizes, int n_in,
                              void* d_out, int out_size, void* d_ws, size_t ws_size,
                              hipStream_t stream) {
  const float* pred = (const float*)d_in[0];
  const float* gt   = (const float*)d_in[1];
  // ws (floats): normals 196608 | partials 64 | packed 65536 float4 | topk 1M ushort
  float*          normals  = (float*)d_ws;
  float*          partials = normals + (size_t)2*NB*NPTS*3;
  float4*         packed   = (float4*)(partials + 64);        // 16B-aligned
  unsigned short* topk     = (unsigned short*)(packed + (size_t)8*NPTS);
  pack_kernel  <<<256,   256, 0, stream>>>(pred, gt, packed);
  select_kernel<<<4096,  256, 0, stream>>>(packed, topk);
  normal_kernel<<<256,   256, 0, stream>>>(packed, topk, normals);
  loss_partial <<<64,    256, 0, stream>>>(normals, partials);
  loss_final   <<<1,      64, 0, stream>>>(partials, (float*)d_out);
}

// Round 10
// 505.708 us; speedup vs baseline: 6.9428x; 1.1309x over previous
//
#include <hip/hip_runtime.h>
#include <math.h>

// NormalConsistencyLoss: B=4, N=8192, D=3, K=16, fp32 in/out (scalar out).
// [pack_kernel]   clouds -> float4(x,y,z,sq).
// [select_kernel] exact 16-NN: analytic radius filter (lambda=32) + wave-shared
//   serial lex (d2,idx) insert (r8-proven); sentinel-validated redo (x2.5, 7
//   rounds -> full-scan guarantee). 8 queries/wave. Bit-identical to lax.top_k.
// [normal_kernel] thread-per-query covariance + faithful LAPACK ssyevd port.
// [loss_partial/loss_final] 1 - mean(dot).

#define NPTS 8192
#define NB   4
#define QPW  8

// ---------------- LAPACK single-precision ports (sign-faithful) ----------------

__device__ __forceinline__ float slapy2f(float x, float y){
#pragma clang fp contract(off)
  float xa = fabsf(x), ya = fabsf(y);
  float w = fmaxf(xa, ya), z = fminf(xa, ya);
  if (z == 0.f) return w;
  float t = z / w;
  return w * sqrtf(1.f + t*t);
}

// LAPACK >= 3.10 slartg
__device__ __forceinline__ void slartgf(float f, float g, float& c, float& s, float& r){
#pragma clang fp contract(off)
  const float safmin = 1.17549435e-38f;
  const float safmax = 8.50705917e37f;
  const float rtmin  = 1.08420217e-19f;
  const float rtmax  = 6.52318604e18f;
  if (g == 0.f){ c = 1.f; s = 0.f; r = f; }
  else if (f == 0.f){ c = 0.f; s = copysignf(1.f, g); r = fabsf(g); }
  else {
    float f1 = fabsf(f), g1 = fabsf(g);
    if (f1 > rtmin && f1 < rtmax && g1 > rtmin && g1 < rtmax){
      float d = sqrtf(f*f + g*g);
      c = f1 / d;
      r = copysignf(d, f);
      s = g / r;
    } else {
      float u = fminf(safmax, fmaxf(safmin, fmaxf(f1, g1)));
      float fs = f/u, gs = g/u;
      float d = sqrtf(fs*fs + gs*gs);
      c = fabsf(fs)/d;
      r = copysignf(d, f);
      r = r*u;
      s = g/r;
    }
  }
}

__device__ __forceinline__ void slaev2f(float a, float b, float cc,
                                        float& rt1, float& rt2, float& cs1, float& sn1){
#pragma clang fp contract(off)
  float sm  = a + cc;
  float df  = a - cc;
  float adf = fabsf(df);
  float tb  = b + b;
  float ab  = fabsf(tb);
  float acmx, acmn;
  if (fabsf(a) > fabsf(cc)){ acmx = a; acmn = cc; } else { acmx = cc; acmn = a; }
  float rt;
  if (adf > ab){ float t = ab/adf; rt = adf*sqrtf(1.f + t*t); }
  else if (adf < ab){ float t = adf/ab; rt = ab*sqrtf(1.f + t*t); }
  else rt = ab*sqrtf(2.f);
  int sgn1;
  if (sm < 0.f){ rt1 = 0.5f*(sm - rt); sgn1 = -1; rt2 = (acmx/rt1)*acmn - (b/rt1)*b; }
  else if (sm > 0.f){ rt1 = 0.5f*(sm + rt); sgn1 = 1; rt2 = (acmx/rt1)*acmn - (b/rt1)*b; }
  else { rt1 = 0.5f*rt; rt2 = -0.5f*rt; sgn1 = 1; }
  int sgn2; float cs;
  if (df >= 0.f){ cs = df + rt; sgn2 = 1; } else { cs = df - rt; sgn2 = -1; }
  float acs = fabsf(cs);
  if (acs > ab){ float ct = -tb/cs; sn1 = 1.f/sqrtf(1.f + ct*ct); cs1 = ct*sn1; }
  else {
    if (ab == 0.f){ cs1 = 1.f; sn1 = 0.f; }
    else { float tn = -cs/tb; cs1 = 1.f/sqrtf(1.f + tn*tn); sn1 = tn*cs1; }
  }
  if (sgn1 == sgn2){ float tn = cs1; cs1 = -sn1; sn1 = tn; }
}

__device__ __forceinline__ void rot2(float z[3][3], int ja, float c, float s){
#pragma clang fp contract(off)
  #pragma unroll
  for (int i = 0; i < 3; ++i){
    float t1 = z[i][ja+1];
    float t0 = z[i][ja];
    z[i][ja+1] = c*t1 - s*t0;
    z[i][ja]   = s*t1 + c*t0;
  }
}

// Faithful port of LAPACK ssteqr('I', n=3, d, e, z)
__device__ __noinline__ void ssteqr3(float* d, float* e, float z[3][3]){
#pragma clang fp contract(off)
  const float eps    = 5.96046448e-08f;
  const float eps2   = 3.55271368e-15f;
  const float safmin = 1.17549435e-38f;
  const float ssfmax = 3.07445735e+18f;
  const float ssfmin = 3.05175781e-05f;
  const int n = 3;
  float cw[2], sw[2];
  int nmaxit, jtot, l1, l, lsv, lend, lendsv, m, iscale, i, j, ii, k;
  float anorm, p, g, r, c, s, f, b, rt1, rt2, tst, mul;

  for (i = 0; i < 3; ++i) for (j = 0; j < 3; ++j) z[i][j] = (i == j) ? 1.f : 0.f;
  nmaxit = n*30; jtot = 0; l1 = 1; m = 0; iscale = 0; anorm = 0.f;
  lsv = 1; lendsv = 1; lend = 1; l = 1;

L10:
  if (l1 > n) goto L160;
  if (l1 > 1) e[l1-2] = 0.f;
  if (l1 <= n-1){
    for (m = l1; m <= n-1; ++m){
      tst = fabsf(e[m-1]);
      if (tst == 0.f) goto L30;
      if (tst <= (sqrtf(fabsf(d[m-1]))*sqrtf(fabsf(d[m])))*eps){ e[m-1] = 0.f; goto L30; }
    }
  }
  m = n;
L30:
  l = l1; lsv = l; lend = m; lendsv = lend; l1 = m + 1;
  if (lend == l) goto L10;
  anorm = 0.f;
  for (i = l; i <= lend; ++i)   anorm = fmaxf(anorm, fabsf(d[i-1]));
  for (i = l; i <= lend-1; ++i) anorm = fmaxf(anorm, fabsf(e[i-1]));
  iscale = 0;
  if (anorm == 0.f) goto L10;
  if (anorm > ssfmax){
    iscale = 1; mul = ssfmax/anorm;
    for (i = l; i <= lend; ++i)   d[i-1] *= mul;
    for (i = l; i <= lend-1; ++i) e[i-1] *= mul;
  } else if (anorm < ssfmin){
    iscale = 2; mul = ssfmin/anorm;
    for (i = l; i <= lend; ++i)   d[i-1] *= mul;
    for (i = l; i <= lend-1; ++i) e[i-1] *= mul;
  }
  if (fabsf(d[lend-1]) < fabsf(d[l-1])){ lend = lsv; l = lendsv; }

  if (lend > l){
L40:
    if (l != lend){
      for (m = l; m <= lend-1; ++m){
        tst = fabsf(e[m-1]); tst = tst*tst;
        if (tst <= (eps2*fabsf(d[m-1]))*fabsf(d[m]) + safmin) goto L60;
      }
    }
    m = lend;
L60:
    if (m < lend) e[m-1] = 0.f;
    p = d[l-1];
    if (m == l) goto L80;
    if (m == l+1){
      slaev2f(d[l-1], e[l-1], d[l], rt1, rt2, c, s);
      rot2(z, l-1, c, s);
      d[l-1] = rt1; d[l] = rt2; e[l-1] = 0.f;
      l += 2;
      if (l <= lend) goto L40;
      goto L140;
    }
    if (jtot == nmaxit) goto L140;
    jtot++;
    g = (d[l] - p)/(2.f*e[l-1]);
    r = slapy2f(g, 1.f);
    g = d[m-1] - p + (e[l-1]/(g + copysignf(r, g)));
    s = 1.f; c = 1.f; p = 0.f;
    for (i = m-1; i >= l; --i){
      f = s*e[i-1];
      b = c*e[i-1];
      slartgf(g, f, c, s, r);
      if (i != m-1) e[i] = r;
      g = d[i] - p;
      r = (d[i-1] - g)*s + 2.f*c*b;
      p = s*r;
      d[i] = g + p;
      g = c*r - b;
      cw[i-l] = c; sw[i-l] = -s;
    }
    for (j = m-l; j >= 1; --j) rot2(z, l+j-2, cw[j-1], sw[j-1]);
    d[l-1] = d[l-1] - p;
    e[l-1] = g;
    goto L40;
L80:
    d[l-1] = p;
    l += 1;
    if (l <= lend) goto L40;
    goto L140;
  } else {
L90:
    if (l != lend){
      for (m = l; m >= lend+1; --m){
        tst = fabsf(e[m-2]); tst = tst*tst;
        if (tst <= (eps2*fabsf(d[m-1]))*fabsf(d[m-2]) + safmin) goto L110;
      }
    }
    m = lend;
L110:
    if (m > lend) e[m-2] = 0.f;
    p = d[l-1];
    if (m == l) goto L130;
    if (m == l-1){
      slaev2f(d[l-2], e[l-2], d[l-1], rt1, rt2, c, s);
      rot2(z, l-2, c, s);
      d[l-2] = rt1; d[l-1] = rt2; e[l-2] = 0.f;
      l -= 2;
      if (l >= lend) goto L90;
      goto L140;
    }
    if (jtot == nmaxit) goto L140;
    jtot++;
    g = (d[l-2] - p)/(2.f*e[l-2]);
    r = slapy2f(g, 1.f);
    g = d[m-1] - p + (e[l-2]/(g + copysignf(r, g)));
    s = 1.f; c = 1.f; p = 0.f;
    for (i = m; i <= l-1; ++i){
      f = s*e[i-1];
      b = c*e[i-1];
      slartgf(g, f, c, s, r);
      if (i != m) e[i-2] = r;
      g = d[i-1] - p;
      r = (d[i] - g)*s + 2.f*c*b;
      p = s*r;
      d[i-1] = g + p;
      g = c*r - b;
      cw[i-m] = c; sw[i-m] = s;
    }
    for (j = 1; j <= l-m; ++j) rot2(z, m+j-2, cw[j-1], sw[j-1]);
    d[l-1] = d[l-1] - p;
    e[l-2] = g;
    goto L90;
L130:
    d[l-1] = p;
    l -= 1;
    if (l >= lend) goto L90;
    goto L140;
  }
L140:
  if (iscale == 1){
    mul = anorm/ssfmax;
    for (i = lsv; i <= lendsv; ++i)   d[i-1] *= mul;
    for (i = lsv; i <= lendsv-1; ++i) e[i-1] *= mul;
  } else if (iscale == 2){
    mul = anorm/ssfmin;
    for (i = lsv; i <= lendsv; ++i)   d[i-1] *= mul;
    for (i = lsv; i <= lendsv-1; ++i) e[i-1] *= mul;
  }
  if (jtot < nmaxit) goto L10;
  return;
L160:
  for (ii = 2; ii <= n; ++ii){
    i = ii - 1; k = i; p = d[i-1];
    for (j = ii; j <= n; ++j){
      if (d[j-1] < p){ k = j; p = d[j-1]; }
    }
    if (k != i){
      d[k-1] = d[i-1]; d[i-1] = p;
      for (j = 0; j < 3; ++j){ float t = z[j][i-1]; z[j][i-1] = z[j][k-1]; z[j][k-1] = t; }
    }
  }
}

__device__ __noinline__ void eigh3_normal(float a11, float a21, float a31,
                                          float a22, float a32, float a33,
                                          float* out3){
#pragma clang fp contract(off)
  float d[3], e[2], z[3][3];
  float tau1 = 0.f, v2 = 0.f;
  float alpha = a21;
  float xnorm = fabsf(a31);
  if (xnorm == 0.f){
    e[0] = alpha;
    tau1 = 0.f;
  } else {
    float beta = -copysignf(slapy2f(alpha, xnorm), alpha);
    tau1 = (beta - alpha)/beta;
    v2 = a31*(1.f/(alpha - beta));
    float x1 = tau1*a22 + tau1*(a32*v2);
    float x2 = tau1*a32 + (tau1*v2)*a33;
    float al = -0.5f*tau1*(x1 + x2*v2);
    float w1 = x1 + al;
    float w2 = x2 + al*v2;
    a22 = a22 - w1 - w1;
    a32 = a32 - v2*w1 - w2;
    a33 = a33 - v2*w2 - w2*v2;
    e[0] = beta;
  }
  e[1] = a32;
  d[0] = a11; d[1] = a22; d[2] = a33;
  ssteqr3(d, e, z);
  if (tau1 != 0.f){
    #pragma unroll
    for (int jj = 0; jj < 3; ++jj){
      float wj  = z[1][jj] + v2*z[2][jj];
      float tmp = tau1*wj;
      z[1][jj] = z[1][jj] - tmp;
      z[2][jj] = z[2][jj] - v2*tmp;
    }
  }
  out3[0] = z[0][0]; out3[1] = z[1][0]; out3[2] = z[2][0];
}

// ---------------- helpers ----------------

__device__ __forceinline__ float sq3f(float x, float y, float z){
#pragma clang fp contract(off)
  return x*x + y*y + z*z;
}

__device__ __forceinline__ float d2f(float qs, float qx, float qy, float qz, float4 c){
#pragma clang fp contract(off)
  float dot = qx*c.x + qy*c.y + qz*c.z;
  return (qs + c.w) - 2.f*dot;
}

// ---------------- kernels ----------------

// Pack clouds as float4(x,y,z,sq). 65536 points total.
__global__ __launch_bounds__(256) void pack_kernel(const float* __restrict__ pred,
                                                   const float* __restrict__ gt,
                                                   float4* __restrict__ packed){
#pragma clang fp contract(off)
  int i = blockIdx.x*256 + threadIdx.x;        // 0..65535
  int cloud = i >> 13;                         // 0..7 (0-3 pred, 4-7 gt)
  int p = i & 8191;
  const float* base = ((cloud >> 2) ? gt : pred) + (size_t)(cloud & 3)*(NPTS*3);
  float x = base[p*3+0], y = base[p*3+1], z = base[p*3+2];
  packed[i] = make_float4(x, y, z, sq3f(x, y, z));
}

// One wave = 8 queries. Wave-shared top-16 per query (lanes 0-15, ascending
// lex (d2,idx)); candidates enter the serial insert chain only if
// dd <= thrA (analytic lambda=32 radius). If slot 15 is still sentinel after
// a scan, redo that query from scratch with thrA*2.5 (7 rounds => thr > max
// possible d2 => unconditional full scan => exactness guaranteed).
__global__ __launch_bounds__(256) void select_kernel(const float4* __restrict__ packed,
                                                     unsigned short* __restrict__ topk){
#pragma clang fp contract(off)
  const int tid  = threadIdx.x;
  const int lane = tid & 63;
  const int g    = blockIdx.x*4 + (tid >> 6);   // wave id 0..8191
  const int qbase = g*QPW;
  const int pc   = qbase >> 13;                 // cloud 0..7
  const float4* __restrict__ cp = packed + (size_t)pc*NPTS;
  const int q0 = qbase & 8191;

  float4 qv[QPW];
  #pragma unroll
  for (int k = 0; k < QPW; ++k) qv[k] = cp[q0 + k];

  // analytic threshold: target lambda=32 for N(0,1)^3 cloud, clamp for tails
  float thrA[QPW];
  #pragma unroll
  for (int k = 0; k < QPW; ++k)
    thrA[k] = fminf(0.0599f * __expf(qv[k].w * 0.33333334f), 0.8f);

  float bd[QPW]; int bi[QPW]; float t16[QPW]; int tI[QPW];
  bool done[QPW];
  #pragma unroll
  for (int k = 0; k < QPW; ++k) done[k] = false;

#define EV_INSERT(K, ddv, iv) {                                               \
    unsigned long long m = __ballot((ddv) <= thrA[K]);                        \
    while (m){                                                                \
      int s = __ffsll(m) - 1;                                                 \
      m &= m - 1;                                                             \
      float dds = __shfl((ddv), s);                                           \
      int idxs = (iv) + s;                                                    \
      if ((dds < t16[K]) || (dds == t16[K] && idxs < tI[K])){                 \
        bool less = (bd[K] < dds) || (bd[K] == dds && bi[K] < idxs);          \
        unsigned long long lm = __ballot(less) & 0xFFFFull;                   \
        int pos = __popcll(lm);                                               \
        float bup = __shfl_up(bd[K], 1);                                      \
        int   iup = __shfl_up(bi[K], 1);                                      \
        bool tn = (lane == pos);                                              \
        bool tu = (lane > pos) && (lane < 16);                                \
        bd[K] = tn ? dds  : (tu ? bup : bd[K]);                               \
        bi[K] = tn ? idxs : (tu ? iup : bi[K]);                               \
        t16[K] = __shfl(bd[K], 15);                                           \
        tI[K]  = __shfl(bi[K], 15);                                           \
      }                                                                       \
    }                                                                         \
  }

  // ---- round 0: all queries active (no done checks in hot loop) ----
  #pragma unroll
  for (int k = 0; k < QPW; ++k){
    bd[k] = 3.0e38f; bi[k] = 0x7fffffff; t16[k] = 3.0e38f; tI[k] = 0x7fffffff;
  }
  for (int it = 0; it < NPTS/64; ++it){
    const int b0 = it*64;
    float4 cd = cp[b0 + lane];
    #pragma unroll
    for (int k = 0; k < QPW; ++k){
      float dd = d2f(qv[k].w, qv[k].x, qv[k].y, qv[k].z, cd);
      EV_INSERT(k, dd, b0)
    }
  }
  {
    bool anyUndone = false;
    #pragma unroll
    for (int k = 0; k < QPW; ++k){
      if (t16[k] < 3.0e38f) done[k] = true;
      else { thrA[k] = thrA[k]*2.5f + 1e-3f; anyUndone = true; }
    }
    // ---- redo rounds (rare; wave-uniform) ----
    for (int round = 1; round < 7 && anyUndone; ++round){
      #pragma unroll
      for (int k = 0; k < QPW; ++k) if (!done[k]){
        bd[k] = 3.0e38f; bi[k] = 0x7fffffff; t16[k] = 3.0e38f; tI[k] = 0x7fffffff;
      }
      for (int it = 0; it < NPTS/64; ++it){
        const int b0 = it*64;
        float4 cd = cp[b0 + lane];
        #pragma unroll
        for (int k = 0; k < QPW; ++k){
          if (done[k]) continue;                 // wave-uniform branch
          float dd = d2f(qv[k].w, qv[k].x, qv[k].y, qv[k].z, cd);
          EV_INSERT(k, dd, b0)
        }
      }
      anyUndone = false;
      #pragma unroll
      for (int k = 0; k < QPW; ++k) if (!done[k]){
        if (t16[k] < 3.0e38f) done[k] = true;
        else { thrA[k] = thrA[k]*2.5f + 1e-3f; anyUndone = true; }
      }
    }
  }
#undef EV_INSERT

  if (lane < 16){
    #pragma unroll
    for (int k = 0; k < QPW; ++k)
      topk[(size_t)(qbase + k)*16 + lane] = (unsigned short)bi[k];
  }
}

// Thread per query: gather 16 neighbors (top_k order), covariance, eigh.
__global__ __launch_bounds__(256) void normal_kernel(const float4* __restrict__ packed,
                                                     const unsigned short* __restrict__ topk,
                                                     float* __restrict__ normals){
#pragma clang fp contract(off)
  const int gq = blockIdx.x*256 + threadIdx.x;   // 0..65535
  const int pc = gq >> 13;
  const float4* __restrict__ cp = packed + (size_t)pc*NPTS;
  const unsigned short* __restrict__ tk = topk + (size_t)gq*16;

  float gxx[16], gyy[16], gzz[16];
  #pragma unroll
  for (int r = 0; r < 16; ++r){
    float4 p = cp[tk[r]];
    gxx[r] = p.x; gyy[r] = p.y; gzz[r] = p.z;
  }
  float mx = 0.f, my = 0.f, mz = 0.f;
  #pragma unroll
  for (int r = 0; r < 16; ++r){ mx += gxx[r]; my += gyy[r]; mz += gzz[r]; }
  mx *= 0.0625f; my *= 0.0625f; mz *= 0.0625f;

  float c00=0.f, c10=0.f, c20=0.f, c11=0.f, c21=0.f, c22=0.f;
  #pragma unroll
  for (int r = 0; r < 16; ++r){
    float cx = gxx[r]-mx, cy = gyy[r]-my, cz = gzz[r]-mz;
    c00 += cx*cx; c10 += cy*cx; c20 += cz*cx;
    c11 += cy*cy; c21 += cz*cy; c22 += cz*cz;
  }
  c00 *= 0.0625f; c10 *= 0.0625f; c20 *= 0.0625f;
  c11 *= 0.0625f; c21 *= 0.0625f; c22 *= 0.0625f;

  float nrm[3];
  eigh3_normal(c00, c10, c20, c11, c21, c22, nrm);

  float* o = normals + (size_t)gq*3;
  o[0] = nrm[0]; o[1] = nrm[1]; o[2] = nrm[2];
}

// ---------------- loss ----------------

__global__ __launch_bounds__(256) void loss_partial(const float* __restrict__ normals,
                                                    float* __restrict__ partials){
  __shared__ float red[256];
  const float4* a4 = (const float4*)normals;                        // 24576 float4
  const float4* g4 = (const float4*)(normals + (size_t)NB*NPTS*3);
  float acc = 0.f;
  for (int i = blockIdx.x*256 + threadIdx.x; i < 24576; i += 64*256){
    float4 a = a4[i], g = g4[i];
    acc += a.x*g.x + a.y*g.y + a.z*g.z + a.w*g.w;
  }
  red[threadIdx.x] = acc;
  __syncthreads();
  for (int sft = 128; sft > 0; sft >>= 1){
    if (threadIdx.x < sft) red[threadIdx.x] += red[threadIdx.x + sft];
    __syncthreads();
  }
  if (threadIdx.x == 0) partials[blockIdx.x] = red[0];
}

__global__ void loss_final(const float* __restrict__ partials,
                           float* __restrict__ out){
  float v = partials[threadIdx.x];
  #pragma unroll
  for (int s = 32; s > 0; s >>= 1) v += __shfl_down(v, s, 64);
  if (threadIdx.x == 0) out[0] = 1.f - v*(1.f/32768.f);
}

extern "C" void kernel_launch(void* const* d_in, const int* in_sizes, int n_in,
                              void* d_out, int out_size, void* d_ws, size_t ws_size,
                              hipStream_t stream) {
  const float* pred = (const float*)d_in[0];
  const float* gt   = (const float*)d_in[1];
  // ws (floats): normals 196608 | partials 64 | packed 65536 float4 | topk 1M ushort
  float*          normals  = (float*)d_ws;
  float*          partials = normals + (size_t)2*NB*NPTS*3;
  float4*         packed   = (float4*)(partials + 64);        // 16B-aligned
  unsigned short* topk     = (unsigned short*)(packed + (size_t)8*NPTS);
  pack_kernel  <<<256,  256, 0, stream>>>(pred, gt, packed);
  select_kernel<<<2048, 256, 0, stream>>>(packed, topk);
  normal_kernel<<<256,  256, 0, stream>>>(packed, topk, normals);
  loss_partial <<<64,   256, 0, stream>>>(normals, partials);
  loss_final   <<<1,     64, 0, stream>>>(partials, (float*)d_out);
}

// Round 11
// 381.855 us; speedup vs baseline: 9.1947x; 1.3243x over previous
//
#include <hip/hip_runtime.h>
#include <math.h>

// NormalConsistencyLoss: B=4, N=8192, D=3, K=16, fp32 in/out (scalar out).
// [pack_kernel]   clouds -> float4(x,y,z,sq).
// [select_kernel] exact 16-NN: analytic radius filter (lambda=32) + wave-shared
//   serial lex (d2,idx) insert (r8-proven); sentinel-validated redo (x2.5, 7
//   rounds -> full-scan guarantee). 4 queries/wave (occupancy-optimal, r8/r10
//   A/B: 4q@75%occ beats 8q@29%occ). Bit-identical to lax.top_k.
// [normal_kernel] thread-per-query covariance + faithful LAPACK ssyevd port.
// [loss_partial/loss_final] 1 - mean(dot).

#define NPTS 8192
#define NB   4
#define QPW  4

// ---------------- LAPACK single-precision ports (sign-faithful) ----------------

__device__ __forceinline__ float slapy2f(float x, float y){
#pragma clang fp contract(off)
  float xa = fabsf(x), ya = fabsf(y);
  float w = fmaxf(xa, ya), z = fminf(xa, ya);
  if (z == 0.f) return w;
  float t = z / w;
  return w * sqrtf(1.f + t*t);
}

// LAPACK >= 3.10 slartg
__device__ __forceinline__ void slartgf(float f, float g, float& c, float& s, float& r){
#pragma clang fp contract(off)
  const float safmin = 1.17549435e-38f;
  const float safmax = 8.50705917e37f;
  const float rtmin  = 1.08420217e-19f;
  const float rtmax  = 6.52318604e18f;
  if (g == 0.f){ c = 1.f; s = 0.f; r = f; }
  else if (f == 0.f){ c = 0.f; s = copysignf(1.f, g); r = fabsf(g); }
  else {
    float f1 = fabsf(f), g1 = fabsf(g);
    if (f1 > rtmin && f1 < rtmax && g1 > rtmin && g1 < rtmax){
      float d = sqrtf(f*f + g*g);
      c = f1 / d;
      r = copysignf(d, f);
      s = g / r;
    } else {
      float u = fminf(safmax, fmaxf(safmin, fmaxf(f1, g1)));
      float fs = f/u, gs = g/u;
      float d = sqrtf(fs*fs + gs*gs);
      c = fabsf(fs)/d;
      r = copysignf(d, f);
      r = r*u;
      s = g/r;
    }
  }
}

__device__ __forceinline__ void slaev2f(float a, float b, float cc,
                                        float& rt1, float& rt2, float& cs1, float& sn1){
#pragma clang fp contract(off)
  float sm  = a + cc;
  float df  = a - cc;
  float adf = fabsf(df);
  float tb  = b + b;
  float ab  = fabsf(tb);
  float acmx, acmn;
  if (fabsf(a) > fabsf(cc)){ acmx = a; acmn = cc; } else { acmx = cc; acmn = a; }
  float rt;
  if (adf > ab){ float t = ab/adf; rt = adf*sqrtf(1.f + t*t); }
  else if (adf < ab){ float t = adf/ab; rt = ab*sqrtf(1.f + t*t); }
  else rt = ab*sqrtf(2.f);
  int sgn1;
  if (sm < 0.f){ rt1 = 0.5f*(sm - rt); sgn1 = -1; rt2 = (acmx/rt1)*acmn - (b/rt1)*b; }
  else if (sm > 0.f){ rt1 = 0.5f*(sm + rt); sgn1 = 1; rt2 = (acmx/rt1)*acmn - (b/rt1)*b; }
  else { rt1 = 0.5f*rt; rt2 = -0.5f*rt; sgn1 = 1; }
  int sgn2; float cs;
  if (df >= 0.f){ cs = df + rt; sgn2 = 1; } else { cs = df - rt; sgn2 = -1; }
  float acs = fabsf(cs);
  if (acs > ab){ float ct = -tb/cs; sn1 = 1.f/sqrtf(1.f + ct*ct); cs1 = ct*sn1; }
  else {
    if (ab == 0.f){ cs1 = 1.f; sn1 = 0.f; }
    else { float tn = -cs/tb; cs1 = 1.f/sqrtf(1.f + tn*tn); sn1 = tn*cs1; }
  }
  if (sgn1 == sgn2){ float tn = cs1; cs1 = -sn1; sn1 = tn; }
}

__device__ __forceinline__ void rot2(float z[3][3], int ja, float c, float s){
#pragma clang fp contract(off)
  #pragma unroll
  for (int i = 0; i < 3; ++i){
    float t1 = z[i][ja+1];
    float t0 = z[i][ja];
    z[i][ja+1] = c*t1 - s*t0;
    z[i][ja]   = s*t1 + c*t0;
  }
}

// Faithful port of LAPACK ssteqr('I', n=3, d, e, z)
__device__ __noinline__ void ssteqr3(float* d, float* e, float z[3][3]){
#pragma clang fp contract(off)
  const float eps    = 5.96046448e-08f;
  const float eps2   = 3.55271368e-15f;
  const float safmin = 1.17549435e-38f;
  const float ssfmax = 3.07445735e+18f;
  const float ssfmin = 3.05175781e-05f;
  const int n = 3;
  float cw[2], sw[2];
  int nmaxit, jtot, l1, l, lsv, lend, lendsv, m, iscale, i, j, ii, k;
  float anorm, p, g, r, c, s, f, b, rt1, rt2, tst, mul;

  for (i = 0; i < 3; ++i) for (j = 0; j < 3; ++j) z[i][j] = (i == j) ? 1.f : 0.f;
  nmaxit = n*30; jtot = 0; l1 = 1; m = 0; iscale = 0; anorm = 0.f;
  lsv = 1; lendsv = 1; lend = 1; l = 1;

L10:
  if (l1 > n) goto L160;
  if (l1 > 1) e[l1-2] = 0.f;
  if (l1 <= n-1){
    for (m = l1; m <= n-1; ++m){
      tst = fabsf(e[m-1]);
      if (tst == 0.f) goto L30;
      if (tst <= (sqrtf(fabsf(d[m-1]))*sqrtf(fabsf(d[m])))*eps){ e[m-1] = 0.f; goto L30; }
    }
  }
  m = n;
L30:
  l = l1; lsv = l; lend = m; lendsv = lend; l1 = m + 1;
  if (lend == l) goto L10;
  anorm = 0.f;
  for (i = l; i <= lend; ++i)   anorm = fmaxf(anorm, fabsf(d[i-1]));
  for (i = l; i <= lend-1; ++i) anorm = fmaxf(anorm, fabsf(e[i-1]));
  iscale = 0;
  if (anorm == 0.f) goto L10;
  if (anorm > ssfmax){
    iscale = 1; mul = ssfmax/anorm;
    for (i = l; i <= lend; ++i)   d[i-1] *= mul;
    for (i = l; i <= lend-1; ++i) e[i-1] *= mul;
  } else if (anorm < ssfmin){
    iscale = 2; mul = ssfmin/anorm;
    for (i = l; i <= lend; ++i)   d[i-1] *= mul;
    for (i = l; i <= lend-1; ++i) e[i-1] *= mul;
  }
  if (fabsf(d[lend-1]) < fabsf(d[l-1])){ lend = lsv; l = lendsv; }

  if (lend > l){
L40:
    if (l != lend){
      for (m = l; m <= lend-1; ++m){
        tst = fabsf(e[m-1]); tst = tst*tst;
        if (tst <= (eps2*fabsf(d[m-1]))*fabsf(d[m]) + safmin) goto L60;
      }
    }
    m = lend;
L60:
    if (m < lend) e[m-1] = 0.f;
    p = d[l-1];
    if (m == l) goto L80;
    if (m == l+1){
      slaev2f(d[l-1], e[l-1], d[l], rt1, rt2, c, s);
      rot2(z, l-1, c, s);
      d[l-1] = rt1; d[l] = rt2; e[l-1] = 0.f;
      l += 2;
      if (l <= lend) goto L40;
      goto L140;
    }
    if (jtot == nmaxit) goto L140;
    jtot++;
    g = (d[l] - p)/(2.f*e[l-1]);
    r = slapy2f(g, 1.f);
    g = d[m-1] - p + (e[l-1]/(g + copysignf(r, g)));
    s = 1.f; c = 1.f; p = 0.f;
    for (i = m-1; i >= l; --i){
      f = s*e[i-1];
      b = c*e[i-1];
      slartgf(g, f, c, s, r);
      if (i != m-1) e[i] = r;
      g = d[i] - p;
      r = (d[i-1] - g)*s + 2.f*c*b;
      p = s*r;
      d[i] = g + p;
      g = c*r - b;
      cw[i-l] = c; sw[i-l] = -s;
    }
    for (j = m-l; j >= 1; --j) rot2(z, l+j-2, cw[j-1], sw[j-1]);
    d[l-1] = d[l-1] - p;
    e[l-1] = g;
    goto L40;
L80:
    d[l-1] = p;
    l += 1;
    if (l <= lend) goto L40;
    goto L140;
  } else {
L90:
    if (l != lend){
      for (m = l; m >= lend+1; --m){
        tst = fabsf(e[m-2]); tst = tst*tst;
        if (tst <= (eps2*fabsf(d[m-1]))*fabsf(d[m-2]) + safmin) goto L110;
      }
    }
    m = lend;
L110:
    if (m > lend) e[m-2] = 0.f;
    p = d[l-1];
    if (m == l) goto L130;
    if (m == l-1){
      slaev2f(d[l-2], e[l-2], d[l-1], rt1, rt2, c, s);
      rot2(z, l-2, c, s);
      d[l-2] = rt1; d[l-1] = rt2; e[l-2] = 0.f;
      l -= 2;
      if (l >= lend) goto L90;
      goto L140;
    }
    if (jtot == nmaxit) goto L140;
    jtot++;
    g = (d[l-2] - p)/(2.f*e[l-2]);
    r = slapy2f(g, 1.f);
    g = d[m-1] - p + (e[l-2]/(g + copysignf(r, g)));
    s = 1.f; c = 1.f; p = 0.f;
    for (i = m; i <= l-1; ++i){
      f = s*e[i-1];
      b = c*e[i-1];
      slartgf(g, f, c, s, r);
      if (i != m) e[i-2] = r;
      g = d[i-1] - p;
      r = (d[i] - g)*s + 2.f*c*b;
      p = s*r;
      d[i-1] = g + p;
      g = c*r - b;
      cw[i-m] = c; sw[i-m] = s;
    }
    for (j = 1; j <= l-m; ++j) rot2(z, m+j-2, cw[j-1], sw[j-1]);
    d[l-1] = d[l-1] - p;
    e[l-2] = g;
    goto L90;
L130:
    d[l-1] = p;
    l -= 1;
    if (l >= lend) goto L90;
    goto L140;
  }
L140:
  if (iscale == 1){
    mul = anorm/ssfmax;
    for (i = lsv; i <= lendsv; ++i)   d[i-1] *= mul;
    for (i = lsv; i <= lendsv-1; ++i) e[i-1] *= mul;
  } else if (iscale == 2){
    mul = anorm/ssfmin;
    for (i = lsv; i <= lendsv; ++i)   d[i-1] *= mul;
    for (i = lsv; i <= lendsv-1; ++i) e[i-1] *= mul;
  }
  if (jtot < nmaxit) goto L10;
  return;
L160:
  for (ii = 2; ii <= n; ++ii){
    i = ii - 1; k = i; p = d[i-1];
    for (j = ii; j <= n; ++j){
      if (d[j-1] < p){ k = j; p = d[j-1]; }
    }
    if (k != i){
      d[k-1] = d[i-1]; d[i-1] = p;
      for (j = 0; j < 3; ++j){ float t = z[j][i-1]; z[j][i-1] = z[j][k-1]; z[j][k-1] = t; }
    }
  }
}

__device__ __noinline__ void eigh3_normal(float a11, float a21, float a31,
                                          float a22, float a32, float a33,
                                          float* out3){
#pragma clang fp contract(off)
  float d[3], e[2], z[3][3];
  float tau1 = 0.f, v2 = 0.f;
  float alpha = a21;
  float xnorm = fabsf(a31);
  if (xnorm == 0.f){
    e[0] = alpha;
    tau1 = 0.f;
  } else {
    float beta = -copysignf(slapy2f(alpha, xnorm), alpha);
    tau1 = (beta - alpha)/beta;
    v2 = a31*(1.f/(alpha - beta));
    float x1 = tau1*a22 + tau1*(a32*v2);
    float x2 = tau1*a32 + (tau1*v2)*a33;
    float al = -0.5f*tau1*(x1 + x2*v2);
    float w1 = x1 + al;
    float w2 = x2 + al*v2;
    a22 = a22 - w1 - w1;
    a32 = a32 - v2*w1 - w2;
    a33 = a33 - v2*w2 - w2*v2;
    e[0] = beta;
  }
  e[1] = a32;
  d[0] = a11; d[1] = a22; d[2] = a33;
  ssteqr3(d, e, z);
  if (tau1 != 0.f){
    #pragma unroll
    for (int jj = 0; jj < 3; ++jj){
      float wj  = z[1][jj] + v2*z[2][jj];
      float tmp = tau1*wj;
      z[1][jj] = z[1][jj] - tmp;
      z[2][jj] = z[2][jj] - v2*tmp;
    }
  }
  out3[0] = z[0][0]; out3[1] = z[1][0]; out3[2] = z[2][0];
}

// ---------------- helpers ----------------

__device__ __forceinline__ float sq3f(float x, float y, float z){
#pragma clang fp contract(off)
  return x*x + y*y + z*z;
}

__device__ __forceinline__ float d2f(float qs, float qx, float qy, float qz, float4 c){
#pragma clang fp contract(off)
  float dot = qx*c.x + qy*c.y + qz*c.z;
  return (qs + c.w) - 2.f*dot;
}

// ---------------- kernels ----------------

// Pack clouds as float4(x,y,z,sq). 65536 points total.
__global__ __launch_bounds__(256) void pack_kernel(const float* __restrict__ pred,
                                                   const float* __restrict__ gt,
                                                   float4* __restrict__ packed){
#pragma clang fp contract(off)
  int i = blockIdx.x*256 + threadIdx.x;        // 0..65535
  int cloud = i >> 13;                         // 0..7 (0-3 pred, 4-7 gt)
  int p = i & 8191;
  const float* base = ((cloud >> 2) ? gt : pred) + (size_t)(cloud & 3)*(NPTS*3);
  float x = base[p*3+0], y = base[p*3+1], z = base[p*3+2];
  packed[i] = make_float4(x, y, z, sq3f(x, y, z));
}

// One wave = 4 queries. Wave-shared top-16 per query (lanes 0-15, ascending
// lex (d2,idx)); candidates enter the serial insert chain only if
// dd <= thrA (analytic lambda=32 radius). If slot 15 is still sentinel after
// a scan, redo that query from scratch with thrA*2.5 (7 rounds => thr > max
// possible d2 => unconditional full scan => exactness guaranteed).
__global__ __launch_bounds__(256) void select_kernel(const float4* __restrict__ packed,
                                                     unsigned short* __restrict__ topk){
#pragma clang fp contract(off)
  const int tid  = threadIdx.x;
  const int lane = tid & 63;
  const int g    = blockIdx.x*4 + (tid >> 6);   // wave id 0..16383
  const int qbase = g*QPW;
  const int pc   = qbase >> 13;                 // cloud 0..7
  const float4* __restrict__ cp = packed + (size_t)pc*NPTS;
  const int q0 = qbase & 8191;

  float4 qv[QPW];
  #pragma unroll
  for (int k = 0; k < QPW; ++k) qv[k] = cp[q0 + k];

  // analytic threshold: target lambda=32 for N(0,1)^3 cloud, clamp for tails
  float thrA[QPW];
  #pragma unroll
  for (int k = 0; k < QPW; ++k)
    thrA[k] = fminf(0.0599f * __expf(qv[k].w * 0.33333334f), 0.8f);

  float bd[QPW]; int bi[QPW]; float t16[QPW]; int tI[QPW];
  bool done[QPW];
  #pragma unroll
  for (int k = 0; k < QPW; ++k) done[k] = false;

#define EV_INSERT(K, ddv, iv) {                                               \
    unsigned long long m = __ballot((ddv) <= thrA[K]);                        \
    while (m){                                                                \
      int s = __ffsll(m) - 1;                                                 \
      m &= m - 1;                                                             \
      float dds = __shfl((ddv), s);                                           \
      int idxs = (iv) + s;                                                    \
      if ((dds < t16[K]) || (dds == t16[K] && idxs < tI[K])){                 \
        bool less = (bd[K] < dds) || (bd[K] == dds && bi[K] < idxs);          \
        unsigned long long lm = __ballot(less) & 0xFFFFull;                   \
        int pos = __popcll(lm);                                               \
        float bup = __shfl_up(bd[K], 1);                                      \
        int   iup = __shfl_up(bi[K], 1);                                      \
        bool tn = (lane == pos);                                              \
        bool tu = (lane > pos) && (lane < 16);                                \
        bd[K] = tn ? dds  : (tu ? bup : bd[K]);                               \
        bi[K] = tn ? idxs : (tu ? iup : bi[K]);                               \
        t16[K] = __shfl(bd[K], 15);                                           \
        tI[K]  = __shfl(bi[K], 15);                                           \
      }                                                                       \
    }                                                                         \
  }

  // ---- round 0: all queries active (no done checks in hot loop) ----
  #pragma unroll
  for (int k = 0; k < QPW; ++k){
    bd[k] = 3.0e38f; bi[k] = 0x7fffffff; t16[k] = 3.0e38f; tI[k] = 0x7fffffff;
  }
  for (int it = 0; it < NPTS/64; ++it){
    const int b0 = it*64;
    float4 cd = cp[b0 + lane];
    #pragma unroll
    for (int k = 0; k < QPW; ++k){
      float dd = d2f(qv[k].w, qv[k].x, qv[k].y, qv[k].z, cd);
      EV_INSERT(k, dd, b0)
    }
  }
  {
    bool anyUndone = false;
    #pragma unroll
    for (int k = 0; k < QPW; ++k){
      if (t16[k] < 3.0e38f) done[k] = true;
      else { thrA[k] = thrA[k]*2.5f + 1e-3f; anyUndone = true; }
    }
    // ---- redo rounds (rare; wave-uniform) ----
    for (int round = 1; round < 7 && anyUndone; ++round){
      #pragma unroll
      for (int k = 0; k < QPW; ++k) if (!done[k]){
        bd[k] = 3.0e38f; bi[k] = 0x7fffffff; t16[k] = 3.0e38f; tI[k] = 0x7fffffff;
      }
      for (int it = 0; it < NPTS/64; ++it){
        const int b0 = it*64;
        float4 cd = cp[b0 + lane];
        #pragma unroll
        for (int k = 0; k < QPW; ++k){
          if (done[k]) continue;                 // wave-uniform branch
          float dd = d2f(qv[k].w, qv[k].x, qv[k].y, qv[k].z, cd);
          EV_INSERT(k, dd, b0)
        }
      }
      anyUndone = false;
      #pragma unroll
      for (int k = 0; k < QPW; ++k) if (!done[k]){
        if (t16[k] < 3.0e38f) done[k] = true;
        else { thrA[k] = thrA[k]*2.5f + 1e-3f; anyUndone = true; }
      }
    }
  }
#undef EV_INSERT

  if (lane < 16){
    #pragma unroll
    for (int k = 0; k < QPW; ++k)
      topk[(size_t)(qbase + k)*16 + lane] = (unsigned short)bi[k];
  }
}

// Thread per query: gather 16 neighbors (top_k order), covariance, eigh.
__global__ __launch_bounds__(256) void normal_kernel(const float4* __restrict__ packed,
                                                     const unsigned short* __restrict__ topk,
                                                     float* __restrict__ normals){
#pragma clang fp contract(off)
  const int gq = blockIdx.x*256 + threadIdx.x;   // 0..65535
  const int pc = gq >> 13;
  const float4* __restrict__ cp = packed + (size_t)pc*NPTS;
  const unsigned short* __restrict__ tk = topk + (size_t)gq*16;

  float gxx[16], gyy[16], gzz[16];
  #pragma unroll
  for (int r = 0; r < 16; ++r){
    float4 p = cp[tk[r]];
    gxx[r] = p.x; gyy[r] = p.y; gzz[r] = p.z;
  }
  float mx = 0.f, my = 0.f, mz = 0.f;
  #pragma unroll
  for (int r = 0; r < 16; ++r){ mx += gxx[r]; my += gyy[r]; mz += gzz[r]; }
  mx *= 0.0625f; my *= 0.0625f; mz *= 0.0625f;

  float c00=0.f, c10=0.f, c20=0.f, c11=0.f, c21=0.f, c22=0.f;
  #pragma unroll
  for (int r = 0; r < 16; ++r){
    float cx = gxx[r]-mx, cy = gyy[r]-my, cz = gzz[r]-mz;
    c00 += cx*cx; c10 += cy*cx; c20 += cz*cx;
    c11 += cy*cy; c21 += cz*cy; c22 += cz*cz;
  }
  c00 *= 0.0625f; c10 *= 0.0625f; c20 *= 0.0625f;
  c11 *= 0.0625f; c21 *= 0.0625f; c22 *= 0.0625f;

  float nrm[3];
  eigh3_normal(c00, c10, c20, c11, c21, c22, nrm);

  float* o = normals + (size_t)gq*3;
  o[0] = nrm[0]; o[1] = nrm[1]; o[2] = nrm[2];
}

// ---------------- loss ----------------

__global__ __launch_bounds__(256) void loss_partial(const float* __restrict__ normals,
                                                    float* __restrict__ partials){
  __shared__ float red[256];
  const float4* a4 = (const float4*)normals;                        // 24576 float4
  const float4* g4 = (const float4*)(normals + (size_t)NB*NPTS*3);
  float acc = 0.f;
  for (int i = blockIdx.x*256 + threadIdx.x; i < 24576; i += 64*256){
    float4 a = a4[i], g = g4[i];
    acc += a.x*g.x + a.y*g.y + a.z*g.z + a.w*g.w;
  }
  red[threadIdx.x] = acc;
  __syncthreads();
  for (int sft = 128; sft > 0; sft >>= 1){
    if (threadIdx.x < sft) red[threadIdx.x] += red[threadIdx.x + sft];
    __syncthreads();
  }
  if (threadIdx.x == 0) partials[blockIdx.x] = red[0];
}

__global__ void loss_final(const float* __restrict__ partials,
                           float* __restrict__ out){
  float v = partials[threadIdx.x];
  #pragma unroll
  for (int s = 32; s > 0; s >>= 1) v += __shfl_down(v, s, 64);
  if (threadIdx.x == 0) out[0] = 1.f - v*(1.f/32768.f);
}

extern "C" void kernel_launch(void* const* d_in, const int* in_sizes, int n_in,
                              void* d_out, int out_size, void* d_ws, size_t ws_size,
                              hipStream_t stream) {
  const float* pred = (const float*)d_in[0];
  const float* gt   = (const float*)d_in[1];
  // ws (floats): normals 196608 | partials 64 | packed 65536 float4 | topk 1M ushort
  float*          normals  = (float*)d_ws;
  float*          partials = normals + (size_t)2*NB*NPTS*3;
  float4*         packed   = (float4*)(partials + 64);        // 16B-aligned
  unsigned short* topk     = (unsigned short*)(packed + (size_t)8*NPTS);
  pack_kernel  <<<256,  256, 0, stream>>>(pred, gt, packed);
  select_kernel<<<4096, 256, 0, stream>>>(packed, topk);
  normal_kernel<<<256,  256, 0, stream>>>(packed, topk, normals);
  loss_partial <<<64,   256, 0, stream>>>(normals, partials);
  loss_final   <<<1,     64, 0, stream>>>(partials, (float*)d_out);
}